// Round 15
// baseline (276.797 us; speedup 1.0000x reference)
//
#include <hip/hip_runtime.h>
#include <math.h>

#define Bg   128
#define Ng   256
#define Dg   256
#define Hg   8
#define HDg  32
#define Eg   524288
#define Kg   128
#define BNg  32768
#define SENT 16384   // = Bg*Kg

using bf16x8 = __attribute__((ext_vector_type(8))) short;
using f32x4  = __attribute__((ext_vector_type(4))) float;

// split f32 -> bf16 hi (truncated) + bf16 lo (residual)
__device__ inline void split2(float x, short &h, short &l) {
    unsigned u = __float_as_uint(x);
    h = (short)(u >> 16);
    float hf = __uint_as_float(u & 0xffff0000u);
    float r = x - hf;
    l = (short)(__float_as_uint(r) >> 16);
}
__device__ inline unsigned pack2(short a, short b) {
    return (unsigned)(unsigned short)a | ((unsigned)(unsigned short)b << 16);
}
// async global->LDS, 16B per lane; dst is the WAVE-UNIFORM base (lane*16B added by HW)
__device__ inline void gload16(const void* g, void* l) {
    __builtin_amdgcn_global_load_lds(
        (const __attribute__((address_space(1))) unsigned*)g,
        (__attribute__((address_space(3))) unsigned*)l, 16, 0, 0);
}

// ---------------- P1: split x into hi/lo bf16 ----------------
__global__ __launch_bounds__(256) void split_x(
    const float* __restrict__ x, short* __restrict__ xh, short* __restrict__ xl)
{
    size_t i = ((size_t)blockIdx.x * 256 + threadIdx.x) * 8;
    float4 a = *(const float4*)(x + i);
    float4 b = *(const float4*)(x + i + 4);
    float v[8] = {a.x,a.y,a.z,a.w,b.x,b.y,b.z,b.w};
    short h[8], l[8];
    #pragma unroll
    for (int j = 0; j < 8; ++j) split2(v[j], h[j], l[j]);
    uint4 uh, ul;
    uh.x = pack2(h[0],h[1]); uh.y = pack2(h[2],h[3]);
    uh.z = pack2(h[4],h[5]); uh.w = pack2(h[6],h[7]);
    ul.x = pack2(l[0],l[1]); ul.y = pack2(l[2],l[3]);
    ul.z = pack2(l[4],l[5]); ul.w = pack2(l[6],l[7]);
    *(uint4*)(xh + i) = uh;
    *(uint4*)(xl + i) = ul;
}

// ---------------- P2: transpose + split weights: WT[n][k] = W[k][n] ----------
__global__ __launch_bounds__(256) void wprep(
    const float* __restrict__ Wq, const float* __restrict__ Wk,
    const float* __restrict__ Wv, const float* __restrict__ Wo,
    short* __restrict__ WTh, short* __restrict__ WTl)
{
    __shared__ float t[64][65];
    const int bid = blockIdx.x;          // 0..63
    const int mat = bid >> 4;
    const int kt = (bid >> 2) & 3, nt = bid & 3;
    const float* W = (mat==0) ? Wq : (mat==1) ? Wk : (mat==2) ? Wv : Wo;
    const int tid = threadIdx.x;
    const int r = tid >> 2, c4 = tid & 3;
    #pragma unroll
    for (int i = 0; i < 4; ++i) {
        float4 v = *(const float4*)(W + (size_t)(kt*64 + r)*256 + nt*64 + c4*16 + i*4);
        t[r][c4*16 + i*4 + 0] = v.x; t[r][c4*16 + i*4 + 1] = v.y;
        t[r][c4*16 + i*4 + 2] = v.z; t[r][c4*16 + i*4 + 3] = v.w;
    }
    __syncthreads();
    const int n = r, k0 = c4 * 16;
    short hb[16], lb[16];
    #pragma unroll
    for (int i = 0; i < 16; ++i) split2(t[k0 + i][n], hb[i], lb[i]);
    size_t base = (size_t)mat*65536 + (size_t)(nt*64 + n)*256 + kt*64 + k0;
    uint4 uh0, uh1, ul0, ul1;
    uh0.x=pack2(hb[0],hb[1]);  uh0.y=pack2(hb[2],hb[3]);  uh0.z=pack2(hb[4],hb[5]);  uh0.w=pack2(hb[6],hb[7]);
    uh1.x=pack2(hb[8],hb[9]);  uh1.y=pack2(hb[10],hb[11]);uh1.z=pack2(hb[12],hb[13]);uh1.w=pack2(hb[14],hb[15]);
    ul0.x=pack2(lb[0],lb[1]);  ul0.y=pack2(lb[2],lb[3]);  ul0.z=pack2(lb[4],lb[5]);  ul0.w=pack2(lb[6],lb[7]);
    ul1.x=pack2(lb[8],lb[9]);  ul1.y=pack2(lb[10],lb[11]);ul1.z=pack2(lb[12],lb[13]);ul1.w=pack2(lb[14],lb[15]);
    *(uint4*)&WTh[base]     = uh0; *(uint4*)&WTh[base + 8] = uh1;
    *(uint4*)&WTl[base]     = ul0; *(uint4*)&WTl[base + 8] = ul1;
}

// ---------------- K1: QKV projection, 8-wave, 3-term, async-LDS dbuf --------
__global__ __launch_bounds__(512, 4) void qkv_mm(
    const short* __restrict__ xh, const short* __restrict__ xl,
    const short* __restrict__ WTh, const short* __restrict__ WTl,
    const float* __restrict__ bq, const float* __restrict__ bk, const float* __restrict__ bv,
    short* __restrict__ Qh, short* __restrict__ Ql,
    short* __restrict__ Kh, short* __restrict__ Kl,
    short* __restrict__ Vh, short* __restrict__ Vl)
{
    const int z = blockIdx.z;
    const float* bias = (z==0) ? bq : (z==1) ? bk : bv;
    short* outH       = (z==0) ? Qh : (z==1) ? Kh : Vh;
    short* outL       = (z==0) ? Ql : (z==1) ? Kl : Vl;
    const float scale = (z==0) ? 0.17677669529663687f : 1.0f;
    const short* bth = WTh + (size_t)z * 65536;
    const short* btl = WTl + (size_t)z * 65536;
    __shared__ __align__(16) short lds[2][16384];
    const int tid = threadIdx.x;
    const int lane = tid & 63, w = tid >> 6;
    const int g = lane >> 4, li = lane & 15;
    const int wr = w >> 2, wc = w & 3;
    const int m0 = blockIdx.x * 128, n0 = blockIdx.y * 128;
    const int sr = tid >> 2, sc = (tid & 3) * 8;
    const int wbase = w * 512;
    f32x4 acc[4][2];
    #pragma unroll
    for (int i = 0; i < 4; ++i)
        #pragma unroll
        for (int j = 0; j < 2; ++j) acc[i][j] = (f32x4){0.f,0.f,0.f,0.f};

    {
        size_t ga = (size_t)(m0 + sr)*256 + sc;
        size_t gb = (size_t)(n0 + sr)*256 + sc;
        gload16(xh + ga,  &lds[0][        wbase]);
        gload16(xl + ga,  &lds[0][ 4096 + wbase]);
        gload16(bth + gb, &lds[0][ 8192 + wbase]);
        gload16(btl + gb, &lds[0][12288 + wbase]);
    }
    __syncthreads();

    for (int k = 0; k < 8; ++k) {
        const int cur = k & 1;
        if (k < 7) {
            const int nb = cur ^ 1;
            int k0n = (k+1)*32;
            size_t ga = (size_t)(m0 + sr)*256 + k0n + sc;
            size_t gb = (size_t)(n0 + sr)*256 + k0n + sc;
            gload16(xh + ga,  &lds[nb][        wbase]);
            gload16(xl + ga,  &lds[nb][ 4096 + wbase]);
            gload16(bth + gb, &lds[nb][ 8192 + wbase]);
            gload16(btl + gb, &lds[nb][12288 + wbase]);
        }
        bf16x8 ah[4], al[4], bh[2], bl[2];
        #pragma unroll
        for (int i = 0; i < 4; ++i) {
            int row = wr*64 + i*16 + li;
            ah[i] = *(const bf16x8*)&lds[cur][       row*32 + g*8];
            al[i] = *(const bf16x8*)&lds[cur][4096 + row*32 + g*8];
        }
        #pragma unroll
        for (int j = 0; j < 2; ++j) {
            int row = wc*32 + j*16 + li;
            bh[j] = *(const bf16x8*)&lds[cur][ 8192 + row*32 + g*8];
            bl[j] = *(const bf16x8*)&lds[cur][12288 + row*32 + g*8];
        }
        #pragma unroll
        for (int i = 0; i < 4; ++i)
            #pragma unroll
            for (int j = 0; j < 2; ++j) {
                acc[i][j] = __builtin_amdgcn_mfma_f32_16x16x32_bf16(bh[j], ah[i], acc[i][j], 0,0,0);
                acc[i][j] = __builtin_amdgcn_mfma_f32_16x16x32_bf16(bl[j], ah[i], acc[i][j], 0,0,0);
                acc[i][j] = __builtin_amdgcn_mfma_f32_16x16x32_bf16(bh[j], al[i], acc[i][j], 0,0,0);
            }
        __syncthreads();
    }
    #pragma unroll
    for (int i = 0; i < 4; ++i) {
        int mrow = m0 + wr*64 + i*16 + li;
        int b = mrow >> 8, nn = mrow & 255;
        #pragma unroll
        for (int j = 0; j < 2; ++j) {
            int c0 = n0 + wc*32 + j*16 + g*4;
            int h = c0 >> 5, hd = c0 & 31;
            float4 bi = *(const float4*)(bias + c0);
            float v0 = (acc[i][j][0] + bi.x) * scale;
            float v1 = (acc[i][j][1] + bi.y) * scale;
            float v2 = (acc[i][j][2] + bi.z) * scale;
            float v3 = (acc[i][j][3] + bi.w) * scale;
            short h0,l0,h1,l1,h2,l2,h3,l3;
            split2(v0,h0,l0); split2(v1,h1,l1); split2(v2,h2,l2); split2(v3,h3,l3);
            uint2 hiq, loq;
            hiq.x = pack2(h0,h1); hiq.y = pack2(h2,h3);
            loq.x = pack2(l0,l1); loq.y = pack2(l2,l3);
            size_t idx = ((size_t)(b*Hg + h)*Ng + nn)*HDg + hd;
            *(uint2*)&outH[idx] = hiq;
            *(uint2*)&outL[idx] = loq;
        }
    }
}

// ---------------- K2: MFMA flash attention (8 waves, dist reg-prefetch) -----
__global__ __launch_bounds__(512, 4) void attn_mfma(
    const short* __restrict__ Qh, const short* __restrict__ Ql,
    const short* __restrict__ Kh, const short* __restrict__ Kl,
    const short* __restrict__ Vh, const short* __restrict__ Vl,
    const float* __restrict__ dist,
    short* __restrict__ AOh, short* __restrict__ AOl)
{
    __shared__ __align__(16) short Khi [2][32][40];
    __shared__ __align__(16) short Klo [2][32][40];
    __shared__ __align__(16) short Vthi[2][32][40];
    __shared__ __align__(16) short Vtlo[2][32][40];
    __shared__ __align__(16) short Phi [8][32][40];
    __shared__ __align__(16) short Plo [8][32][40];

    const int i0 = blockIdx.x;
    const int xcd = i0 & 7;
    const int m_  = i0 >> 3;
    const int h   = m_ & 7;
    const int b   = (m_ >> 3) * 8 + xcd;
    const int bh  = b * 8 + h;

    const int tid = threadIdx.x;
    const int w = tid >> 6;
    const int lane = tid & 63;
    const int g = lane >> 4;
    const int li = lane & 15;
    const int q0 = w * 32;
    const int skey = tid >> 4;
    const int se0  = (tid & 15) * 2;
    const float* dall = dist + (size_t)b*Ng*Ng;

    bf16x8 qh[2], ql[2];
    #pragma unroll
    for (int tq = 0; tq < 2; ++tq) {
        size_t qoff = ((size_t)bh * Ng + q0 + tq*16 + li) * HDg + g*8;
        qh[tq] = *(const bf16x8*)(Qh + qoff);
        ql[tq] = *(const bf16x8*)(Ql + qoff);
    }

    f32x4 dA[2][2], dB[2][2];
    // prologue: dist chunk 0 -> dA; stage K/V chunk 0 -> buf 0
    #pragma unroll
    for (int tq = 0; tq < 2; ++tq)
        #pragma unroll
        for (int tc = 0; tc < 2; ++tc) {
            const float* dp = dall + (size_t)(q0 + tq*16 + li)*Ng + tc*16 + g*4;
            float4 dv = *(const float4*)dp;
            dA[tq][tc] = (f32x4){dv.x, dv.y, dv.z, dv.w};
        }
    {
        size_t koff = ((size_t)bh*Ng + skey) * HDg + se0;
        unsigned kh1 = *(const unsigned*)(Kh + koff);
        unsigned kl1 = *(const unsigned*)(Kl + koff);
        unsigned vh1 = *(const unsigned*)(Vh + koff);
        unsigned vl1 = *(const unsigned*)(Vl + koff);
        *(unsigned*)&Khi[0][skey][se0] = kh1;
        *(unsigned*)&Klo[0][skey][se0] = kl1;
        Vthi[0][se0+0][skey] = (short)(vh1 & 0xffff);
        Vthi[0][se0+1][skey] = (short)(vh1 >> 16);
        Vtlo[0][se0+0][skey] = (short)(vl1 & 0xffff);
        Vtlo[0][se0+1][skey] = (short)(vl1 >> 16);
    }
    __syncthreads();

    f32x4 O[2][2];
    #pragma unroll
    for (int tq=0;tq<2;++tq)
        #pragma unroll
        for (int td=0;td<2;++td) O[tq][td] = (f32x4){0.f,0.f,0.f,0.f};
    float lpart[2] = {0.f, 0.f};

    auto body = [&](int ch, f32x4 (&dcur)[2][2], f32x4 (&dnx)[2][2]) {
        const int cur = ch & 1;
        const bool pref = (ch < 7);
        unsigned khr, klr, vhr, vlr;
        if (pref) {
            // issue next-chunk dist + K/V loads EARLY; consumed after compute
            const float* dbase = dall + (ch+1)*32;
            #pragma unroll
            for (int tq = 0; tq < 2; ++tq)
                #pragma unroll
                for (int tc = 0; tc < 2; ++tc) {
                    const float* dp = dbase + (size_t)(q0 + tq*16 + li)*Ng + tc*16 + g*4;
                    float4 dv = *(const float4*)dp;
                    dnx[tq][tc] = (f32x4){dv.x, dv.y, dv.z, dv.w};
                }
            size_t koff = ((size_t)bh*Ng + (ch+1)*32 + skey) * HDg + se0;
            khr = *(const unsigned*)(Kh + koff);
            klr = *(const unsigned*)(Kl + koff);
            vhr = *(const unsigned*)(Vh + koff);
            vlr = *(const unsigned*)(Vl + koff);
        }
        // S^T = K.Q^T + dist^T (dcur seeds accumulators)
        f32x4 sacc[2][2];
        bf16x8 kbh[2], kbl[2];
        #pragma unroll
        for (int tc = 0; tc < 2; ++tc) {
            kbh[tc] = *(const bf16x8*)&Khi[cur][tc*16+li][g*8];
            kbl[tc] = *(const bf16x8*)&Klo[cur][tc*16+li][g*8];
        }
        #pragma unroll
        for (int tq = 0; tq < 2; ++tq)
            #pragma unroll
            for (int tc = 0; tc < 2; ++tc) {
                sacc[tq][tc] = dcur[tq][tc];
                sacc[tq][tc] = __builtin_amdgcn_mfma_f32_16x16x32_bf16(kbh[tc], qh[tq], sacc[tq][tc], 0,0,0);
                sacc[tq][tc] = __builtin_amdgcn_mfma_f32_16x16x32_bf16(kbl[tc], qh[tq], sacc[tq][tc], 0,0,0);
                sacc[tq][tc] = __builtin_amdgcn_mfma_f32_16x16x32_bf16(kbh[tc], ql[tq], sacc[tq][tc], 0,0,0);
            }
        // softmax -> hi/lo pack -> b64 writes
        #pragma unroll
        for (int tq = 0; tq < 2; ++tq)
            #pragma unroll
            for (int tc = 0; tc < 2; ++tc) {
                float p0 = __expf(sacc[tq][tc][0] - 16.f);
                float p1 = __expf(sacc[tq][tc][1] - 16.f);
                float p2 = __expf(sacc[tq][tc][2] - 16.f);
                float p3 = __expf(sacc[tq][tc][3] - 16.f);
                lpart[tq] += p0; lpart[tq] += p1; lpart[tq] += p2; lpart[tq] += p3;
                unsigned u0 = __float_as_uint(p0), u1 = __float_as_uint(p1);
                unsigned u2 = __float_as_uint(p2), u3 = __float_as_uint(p3);
                float r0 = p0 - __uint_as_float(u0 & 0xffff0000u);
                float r1 = p1 - __uint_as_float(u1 & 0xffff0000u);
                float r2 = p2 - __uint_as_float(u2 & 0xffff0000u);
                float r3 = p3 - __uint_as_float(u3 & 0xffff0000u);
                uint2 hiq, loq;
                hiq.x = (u0 >> 16) | (u1 & 0xffff0000u);
                hiq.y = (u2 >> 16) | (u3 & 0xffff0000u);
                loq.x = (__float_as_uint(r0) >> 16) | (__float_as_uint(r1) & 0xffff0000u);
                loq.y = (__float_as_uint(r2) >> 16) | (__float_as_uint(r3) & 0xffff0000u);
                *(uint2*)&Phi[w][tq*16 + li][tc*16 + g*4] = hiq;
                *(uint2*)&Plo[w][tq*16 + li][tc*16 + g*4] = loq;
            }
        bf16x8 vbh[2], vbl[2];
        #pragma unroll
        for (int td = 0; td < 2; ++td) {
            vbh[td] = *(const bf16x8*)&Vthi[cur][td*16+li][g*8];
            vbl[td] = *(const bf16x8*)&Vtlo[cur][td*16+li][g*8];
        }
        #pragma unroll
        for (int tq = 0; tq < 2; ++tq) {
            bf16x8 ph = *(const bf16x8*)&Phi[w][tq*16+li][g*8];
            bf16x8 pl = *(const bf16x8*)&Plo[w][tq*16+li][g*8];
            #pragma unroll
            for (int td = 0; td < 2; ++td) {
                O[tq][td] = __builtin_amdgcn_mfma_f32_16x16x32_bf16(vbh[td], ph, O[tq][td], 0,0,0);
                O[tq][td] = __builtin_amdgcn_mfma_f32_16x16x32_bf16(vbl[td], ph, O[tq][td], 0,0,0);
                O[tq][td] = __builtin_amdgcn_mfma_f32_16x16x32_bf16(vbh[td], pl, O[tq][td], 0,0,0);
            }
        }
        // write-late K/V staging into alternate buffer
        if (pref) {
            const int nb = cur ^ 1;
            *(unsigned*)&Khi[nb][skey][se0] = khr;
            *(unsigned*)&Klo[nb][skey][se0] = klr;
            Vthi[nb][se0+0][skey] = (short)(vhr & 0xffff);
            Vthi[nb][se0+1][skey] = (short)(vhr >> 16);
            Vtlo[nb][se0+0][skey] = (short)(vlr & 0xffff);
            Vtlo[nb][se0+1][skey] = (short)(vlr >> 16);
        }
        __syncthreads();
    };

    #pragma unroll
    for (int ch8 = 0; ch8 < 8; ch8 += 2) {
        body(ch8,     dA, dB);
        body(ch8 + 1, dB, dA);
    }

    float inv[2];
    #pragma unroll
    for (int tq = 0; tq < 2; ++tq) {
        float s = lpart[tq];
        s += __shfl_xor(s, 16);
        s += __shfl_xor(s, 32);
        inv[tq] = 1.f / s;
    }
    #pragma unroll
    for (int tq = 0; tq < 2; ++tq)
        #pragma unroll
        for (int td = 0; td < 2; ++td) {
            float v0 = O[tq][td][0] * inv[tq];
            float v1 = O[tq][td][1] * inv[tq];
            float v2 = O[tq][td][2] * inv[tq];
            float v3 = O[tq][td][3] * inv[tq];
            unsigned u0 = __float_as_uint(v0), u1 = __float_as_uint(v1);
            unsigned u2 = __float_as_uint(v2), u3 = __float_as_uint(v3);
            float r0 = v0 - __uint_as_float(u0 & 0xffff0000u);
            float r1 = v1 - __uint_as_float(u1 & 0xffff0000u);
            float r2 = v2 - __uint_as_float(u2 & 0xffff0000u);
            float r3 = v3 - __uint_as_float(u3 & 0xffff0000u);
            uint2 hiq, loq;
            hiq.x = (u0 >> 16) | (u1 & 0xffff0000u);
            hiq.y = (u2 >> 16) | (u3 & 0xffff0000u);
            loq.x = (__float_as_uint(r0) >> 16) | (__float_as_uint(r1) & 0xffff0000u);
            loq.y = (__float_as_uint(r2) >> 16) | (__float_as_uint(r3) & 0xffff0000u);
            int q = q0 + tq*16 + li;
            size_t base = ((size_t)b*Ng + q)*Dg + h*HDg + td*16 + g*4;
            *(uint2*)&AOh[base] = hiq;
            *(uint2*)&AOl[base] = loq;
        }
}

// ---------------- K3: output projection + fused pooling-score partials ------
// score_part[p][row], p = blockIdx.y*4 + wc (col chunk of 32); deterministic.
__global__ __launch_bounds__(512, 4) void out_mm(
    const short* __restrict__ aoh, const short* __restrict__ aol,
    const short* __restrict__ bth, const short* __restrict__ btl,
    const float* __restrict__ bo, const float* __restrict__ pw,
    float* __restrict__ enc, float* __restrict__ score_part)
{
    __shared__ __align__(16) short lds[2][16384];
    const int tid = threadIdx.x;
    const int lane = tid & 63, w = tid >> 6;
    const int g = lane >> 4, li = lane & 15;
    const int wr = w >> 2, wc = w & 3;
    const int m0 = blockIdx.x * 128, n0 = blockIdx.y * 128;
    const int sr = tid >> 2, sc = (tid & 3) * 8;
    const int wbase = w * 512;
    f32x4 acc[4][2];
    #pragma unroll
    for (int i = 0; i < 4; ++i)
        #pragma unroll
        for (int j = 0; j < 2; ++j) acc[i][j] = (f32x4){0.f,0.f,0.f,0.f};

    {
        size_t ga = (size_t)(m0 + sr)*256 + sc;
        size_t gb = (size_t)(n0 + sr)*256 + sc;
        gload16(aoh + ga, &lds[0][        wbase]);
        gload16(aol + ga, &lds[0][ 4096 + wbase]);
        gload16(bth + gb, &lds[0][ 8192 + wbase]);
        gload16(btl + gb, &lds[0][12288 + wbase]);
    }
    __syncthreads();

    for (int k = 0; k < 8; ++k) {
        const int cur = k & 1;
        if (k < 7) {
            const int nb = cur ^ 1;
            int k0n = (k+1)*32;
            size_t ga = (size_t)(m0 + sr)*256 + k0n + sc;
            size_t gb = (size_t)(n0 + sr)*256 + k0n + sc;
            gload16(aoh + ga, &lds[nb][        wbase]);
            gload16(aol + ga, &lds[nb][ 4096 + wbase]);
            gload16(bth + gb, &lds[nb][ 8192 + wbase]);
            gload16(btl + gb, &lds[nb][12288 + wbase]);
        }
        bf16x8 ah[4], al[4], bh[2], bl[2];
        #pragma unroll
        for (int i = 0; i < 4; ++i) {
            int row = wr*64 + i*16 + li;
            ah[i] = *(const bf16x8*)&lds[cur][       row*32 + g*8];
            al[i] = *(const bf16x8*)&lds[cur][4096 + row*32 + g*8];
        }
        #pragma unroll
        for (int j = 0; j < 2; ++j) {
            int row = wc*32 + j*16 + li;
            bh[j] = *(const bf16x8*)&lds[cur][ 8192 + row*32 + g*8];
            bl[j] = *(const bf16x8*)&lds[cur][12288 + row*32 + g*8];
        }
        #pragma unroll
        for (int i = 0; i < 4; ++i)
            #pragma unroll
            for (int j = 0; j < 2; ++j) {
                acc[i][j] = __builtin_amdgcn_mfma_f32_16x16x32_bf16(bh[j], ah[i], acc[i][j], 0,0,0);
                acc[i][j] = __builtin_amdgcn_mfma_f32_16x16x32_bf16(bl[j], ah[i], acc[i][j], 0,0,0);
                acc[i][j] = __builtin_amdgcn_mfma_f32_16x16x32_bf16(bh[j], al[i], acc[i][j], 0,0,0);
            }
        __syncthreads();
    }
    const int pslot = blockIdx.y * 4 + wc;
    #pragma unroll
    for (int i = 0; i < 4; ++i) {
        int mrow = m0 + wr*64 + i*16 + li;
        float s = 0.f;
        #pragma unroll
        for (int j = 0; j < 2; ++j) {
            int c0 = n0 + wc*32 + j*16 + g*4;
            float4 bo4 = *(const float4*)(bo + c0);
            float4 pw4 = *(const float4*)(pw + c0);
            float4 v;
            v.x = acc[i][j][0] + bo4.x;
            v.y = acc[i][j][1] + bo4.y;
            v.z = acc[i][j][2] + bo4.z;
            v.w = acc[i][j][3] + bo4.w;
            *(float4*)&enc[(size_t)mrow*Dg + c0] = v;
            s += v.x*pw4.x + v.y*pw4.y + v.z*pw4.z + v.w*pw4.w;
        }
        s += __shfl_xor(s, 16);
        s += __shfl_xor(s, 32);
        if (g == 0) score_part[(size_t)pslot * BNg + mrow] = s;
    }
}

// ---------------- norm ----------------
__global__ void norm_kernel(const float* __restrict__ pw, float* __restrict__ inv_norm)
{
    int t = threadIdx.x;
    float s = 0.f;
    for (int d = t; d < Dg; d += 64) s = fmaf(pw[d], pw[d], s);
    #pragma unroll
    for (int off = 32; off > 0; off >>= 1) s += __shfl_xor(s, off);
    if (t == 0) *inv_norm = 1.0f / sqrtf(s);
}

// ---------------- K5: per-graph exact top-K via rank count ----------------
__global__ __launch_bounds__(256) void topk_kernel(
    const float* __restrict__ score_part, float* __restrict__ vals, int* __restrict__ idxs,
    int* __restrict__ new_id, float* __restrict__ out_batch)
{
    __shared__ float sh[Ng];
    int bgr = blockIdx.x, t = threadIdx.x;
    int row = bgr * Ng + t;
    float mine = 0.f;
    #pragma unroll
    for (int p = 0; p < 8; ++p) mine += score_part[(size_t)p * BNg + row];
    sh[t] = mine;
    __syncthreads();
    int cnt = 0;
    for (int j = 0; j < Ng; ++j) {
        float v = sh[j];
        cnt += (v > mine || (v == mine && j < t)) ? 1 : 0;
    }
    if (cnt < Kg) {
        int pos = bgr * Kg + cnt;
        vals[pos] = mine;
        idxs[pos] = t;
        new_id[bgr * Ng + t] = pos;
        out_batch[pos] = (float)bgr;
    } else {
        new_id[bgr * Ng + t] = SENT;
    }
}

// ---------------- K6: gather + tanh scale ----------------
__global__ __launch_bounds__(256) void subx_kernel(
    const float* __restrict__ enc, const float* __restrict__ vals,
    const int* __restrict__ idxs, const float* __restrict__ inv_norm,
    float* __restrict__ out_subx)
{
    int j    = blockIdx.x * 4 + (threadIdx.x >> 6);
    int lane = threadIdx.x & 63;
    int bgr  = j >> 7;
    int src  = bgr * Ng + idxs[j];
    float scale = tanhf(vals[j] * (*inv_norm));
    float4 v = reinterpret_cast<const float4*>(enc + (size_t)src * Dg)[lane];
    v.x *= scale; v.y *= scale; v.z *= scale; v.w *= scale;
    reinterpret_cast<float4*>(out_subx + (size_t)j * Dg)[lane] = v;
}

// ---------------- edge pipeline ----------------
__global__ __launch_bounds__(256) void edge_hist(
    const int* __restrict__ ei, const int* __restrict__ new_id, int* __restrict__ counts)
{
    int e = blockIdx.x * 256 + threadIdx.x;
    int r = new_id[ei[e]];
    int c = new_id[ei[Eg + e]];
    if (r != SENT && c != SENT) atomicAdd(&counts[r], 1);
}

__global__ __launch_bounds__(256) void scan_kernel(
    const int* __restrict__ counts, int* __restrict__ offsets)
{
    __shared__ int sums[256];
    int t = threadIdx.x;
    int base = t * 64;
    int s = 0;
    for (int i = 0; i < 64; ++i) s += counts[base + i];
    sums[t] = s;
    __syncthreads();
    for (int off = 1; off < 256; off <<= 1) {
        int add = (t >= off) ? sums[t - off] : 0;
        __syncthreads();
        sums[t] += add;
        __syncthreads();
    }
    int run = sums[t] - s;
    for (int i = 0; i < 64; ++i) { offsets[base + i] = run; run += counts[base + i]; }
    if (t == 255) offsets[SENT] = run;
}

__global__ __launch_bounds__(256) void edge_scatter(
    const int* __restrict__ ei, const int* __restrict__ new_id,
    const int* __restrict__ offsets, int* __restrict__ cursor, int* __restrict__ bucket)
{
    int e = blockIdx.x * 256 + threadIdx.x;
    int r = new_id[ei[e]];
    int c = new_id[ei[Eg + e]];
    if (r != SENT && c != SENT) {
        int pos = offsets[r] + atomicAdd(&cursor[r], 1);
        bucket[pos] = c;
    }
}

__global__ __launch_bounds__(256) void edge_sort_emit(
    const int* __restrict__ offsets, int* bucket, float* __restrict__ out_edges)
{
    int r = blockIdx.x * 256 + threadIdx.x;
    int s = offsets[r], e = offsets[r + 1];
    for (int i = s + 1; i < e; ++i) {
        int key = bucket[i];
        int j = i - 1;
        while (j >= s && bucket[j] > key) { bucket[j+1] = bucket[j]; --j; }
        bucket[j+1] = key;
    }
    float rf = (float)r;
    for (int i = s; i < e; ++i) {
        out_edges[i]      = rf;
        out_edges[Eg + i] = (float)bucket[i];
    }
}

__global__ __launch_bounds__(256) void edge_fill(
    const int* __restrict__ offsets, float* __restrict__ out_edges)
{
    int p = blockIdx.x * 256 + threadIdx.x;
    if (p >= offsets[SENT]) {
        out_edges[p]      = (float)SENT;
        out_edges[Eg + p] = (float)SENT;
    }
}

// ---------------- launch ----------------
extern "C" void kernel_launch(void* const* d_in, const int* in_sizes, int n_in,
                              void* d_out, int out_size, void* d_ws, size_t ws_size,
                              hipStream_t stream)
{
    const float* x    = (const float*)d_in[0];
    const float* dist = (const float*)d_in[2];
    const int*   ei   = (const int*)d_in[3];
    const float* Wq = (const float*)d_in[5];
    const float* bq = (const float*)d_in[6];
    const float* Wk = (const float*)d_in[7];
    const float* bk = (const float*)d_in[8];
    const float* Wv = (const float*)d_in[9];
    const float* bv = (const float*)d_in[10];
    const float* Wo = (const float*)d_in[11];
    const float* bo = (const float*)d_in[12];
    const float* pw = (const float*)d_in[13];

    float* out       = (float*)d_out;
    float* enc_out   = out;                     // [B*N*D]
    float* subx_out  = out + 8388608;           // [B*K*D]
    float* edge_out  = out + 12582912;          // [2*E]
    float* batch_out = out + 13631488;          // [B*K]

    float* ws      = (float*)d_ws;
    short* Qh      = (short*)ws;                 // 8,388,608 shorts each
    short* Ql      = (short*)(ws + 4194304);
    short* Kh      = (short*)(ws + 8388608);
    short* Kl      = (short*)(ws + 12582912);
    short* Vh      = (short*)(ws + 16777216);
    short* Vl      = (short*)(ws + 20971520);
    short* xh      = (short*)(ws + 25165824);    // 8,388,608 shorts
    short* xl      = (short*)(ws + 29360128);
    short* AOh     = xh;                         // alias after split_x consumed
    short* AOl     = xl;
    short* WTh     = (short*)(ws + 33554432);    // 4*65536 shorts
    short* WTl     = (short*)(ws + 33685504);
    float* vals    = ws + 33849344;              // 16384
    int*   idxs    = (int*)(ws + 33865728);      // 16384
    int*   new_id  = (int*)(ws + 33882112);      // 32768
    int*   counts  = (int*)(ws + 33914880);      // 16384
    int*   offsets = (int*)(ws + 33931264);      // 16416
    int*   cursor  = (int*)(ws + 33947680);      // 16384
    float* inv_nm  = ws + 33964064;              // 32
    int*   bucket  = (int*)(ws + 33964096);      // 524288
    float* score_part = ws + 34488384;           // 8*32768 = 262144

    hipMemsetAsync(counts, 0, SENT * sizeof(int), stream);
    hipMemsetAsync(cursor, 0, SENT * sizeof(int), stream);

    split_x       <<<dim3(4096),               256, 0, stream>>>(x, xh, xl);
    wprep         <<<dim3(64),                 256, 0, stream>>>(Wq, Wk, Wv, Wo, WTh, WTl);
    norm_kernel   <<<dim3(1),                   64, 0, stream>>>(pw, inv_nm);
    qkv_mm        <<<dim3(BNg/128, Dg/128, 3), 512, 0, stream>>>(xh, xl, WTh, WTl, bq, bk, bv,
                                                                 Qh, Ql, Kh, Kl, Vh, Vl);
    attn_mfma     <<<dim3(Bg*Hg),              512, 0, stream>>>(Qh, Ql, Kh, Kl, Vh, Vl, dist, AOh, AOl);
    out_mm        <<<dim3(BNg/128, Dg/128),    512, 0, stream>>>(AOh, AOl, WTh + 3*65536, WTl + 3*65536,
                                                                 bo, pw, enc_out, score_part);
    topk_kernel   <<<dim3(Bg),                 256, 0, stream>>>(score_part, vals, idxs, new_id, batch_out);
    subx_kernel   <<<dim3((Bg*Kg)/4),          256, 0, stream>>>(enc_out, vals, idxs, inv_nm, subx_out);
    edge_hist     <<<dim3(Eg/256),             256, 0, stream>>>(ei, new_id, counts);
    scan_kernel   <<<dim3(1),                  256, 0, stream>>>(counts, offsets);
    edge_scatter  <<<dim3(Eg/256),             256, 0, stream>>>(ei, new_id, offsets, cursor, bucket);
    edge_sort_emit<<<dim3(SENT/256),           256, 0, stream>>>(offsets, bucket, edge_out);
    edge_fill     <<<dim3(Eg/256),             256, 0, stream>>>(offsets, edge_out);
    (void)in_sizes; (void)n_in; (void)out_size; (void)ws_size;
}

// Round 16
// 220.860 us; speedup vs baseline: 1.2533x; 1.2533x over previous
//
#include <hip/hip_runtime.h>
#include <math.h>

#define Bg   128
#define Ng   256
#define Dg   256
#define Hg   8
#define HDg  32
#define Eg   524288
#define Kg   128
#define BNg  32768
#define SENT 16384   // = Bg*Kg

using bf16x8 = __attribute__((ext_vector_type(8))) short;
using f32x4  = __attribute__((ext_vector_type(4))) float;

// split f32 -> bf16 hi (truncated) + bf16 lo (residual)
__device__ inline void split2(float x, short &h, short &l) {
    unsigned u = __float_as_uint(x);
    h = (short)(u >> 16);
    float hf = __uint_as_float(u & 0xffff0000u);
    float r = x - hf;
    l = (short)(__float_as_uint(r) >> 16);
}
__device__ inline unsigned pack2(short a, short b) {
    return (unsigned)(unsigned short)a | ((unsigned)(unsigned short)b << 16);
}
// async global->LDS, 16B per lane; dst is the WAVE-UNIFORM base (lane*16B added by HW)
__device__ inline void gload16(const void* g, void* l) {
    __builtin_amdgcn_global_load_lds(
        (const __attribute__((address_space(1))) unsigned*)g,
        (__attribute__((address_space(3))) unsigned*)l, 16, 0, 0);
}

// ---------------- P1: split x into hi/lo bf16 ----------------
__global__ __launch_bounds__(256) void split_x(
    const float* __restrict__ x, short* __restrict__ xh, short* __restrict__ xl)
{
    size_t i = ((size_t)blockIdx.x * 256 + threadIdx.x) * 8;
    float4 a = *(const float4*)(x + i);
    float4 b = *(const float4*)(x + i + 4);
    float v[8] = {a.x,a.y,a.z,a.w,b.x,b.y,b.z,b.w};
    short h[8], l[8];
    #pragma unroll
    for (int j = 0; j < 8; ++j) split2(v[j], h[j], l[j]);
    uint4 uh, ul;
    uh.x = pack2(h[0],h[1]); uh.y = pack2(h[2],h[3]);
    uh.z = pack2(h[4],h[5]); uh.w = pack2(h[6],h[7]);
    ul.x = pack2(l[0],l[1]); ul.y = pack2(l[2],l[3]);
    ul.z = pack2(l[4],l[5]); ul.w = pack2(l[6],l[7]);
    *(uint4*)(xh + i) = uh;
    *(uint4*)(xl + i) = ul;
}

// ---------------- P2: transpose + split weights: WT[n][k] = W[k][n] ----------
__global__ __launch_bounds__(256) void wprep(
    const float* __restrict__ Wq, const float* __restrict__ Wk,
    const float* __restrict__ Wv, const float* __restrict__ Wo,
    short* __restrict__ WTh, short* __restrict__ WTl)
{
    __shared__ float t[64][65];
    const int bid = blockIdx.x;          // 0..63
    const int mat = bid >> 4;
    const int kt = (bid >> 2) & 3, nt = bid & 3;
    const float* W = (mat==0) ? Wq : (mat==1) ? Wk : (mat==2) ? Wv : Wo;
    const int tid = threadIdx.x;
    const int r = tid >> 2, c4 = tid & 3;
    #pragma unroll
    for (int i = 0; i < 4; ++i) {
        float4 v = *(const float4*)(W + (size_t)(kt*64 + r)*256 + nt*64 + c4*16 + i*4);
        t[r][c4*16 + i*4 + 0] = v.x; t[r][c4*16 + i*4 + 1] = v.y;
        t[r][c4*16 + i*4 + 2] = v.z; t[r][c4*16 + i*4 + 3] = v.w;
    }
    __syncthreads();
    const int n = r, k0 = c4 * 16;
    short hb[16], lb[16];
    #pragma unroll
    for (int i = 0; i < 16; ++i) split2(t[k0 + i][n], hb[i], lb[i]);
    size_t base = (size_t)mat*65536 + (size_t)(nt*64 + n)*256 + kt*64 + k0;
    uint4 uh0, uh1, ul0, ul1;
    uh0.x=pack2(hb[0],hb[1]);  uh0.y=pack2(hb[2],hb[3]);  uh0.z=pack2(hb[4],hb[5]);  uh0.w=pack2(hb[6],hb[7]);
    uh1.x=pack2(hb[8],hb[9]);  uh1.y=pack2(hb[10],hb[11]);uh1.z=pack2(hb[12],hb[13]);uh1.w=pack2(hb[14],hb[15]);
    ul0.x=pack2(lb[0],lb[1]);  ul0.y=pack2(lb[2],lb[3]);  ul0.z=pack2(lb[4],lb[5]);  ul0.w=pack2(lb[6],lb[7]);
    ul1.x=pack2(lb[8],lb[9]);  ul1.y=pack2(lb[10],lb[11]);ul1.z=pack2(lb[12],lb[13]);ul1.w=pack2(lb[14],lb[15]);
    *(uint4*)&WTh[base]     = uh0; *(uint4*)&WTh[base + 8] = uh1;
    *(uint4*)&WTl[base]     = ul0; *(uint4*)&WTl[base + 8] = ul1;
}

// ---------------- K1: QKV projection, 8-wave, 3-term, async-LDS dbuf --------
__global__ __launch_bounds__(512, 4) void qkv_mm(
    const short* __restrict__ xh, const short* __restrict__ xl,
    const short* __restrict__ WTh, const short* __restrict__ WTl,
    const float* __restrict__ bq, const float* __restrict__ bk, const float* __restrict__ bv,
    short* __restrict__ Qh, short* __restrict__ Ql,
    short* __restrict__ Kh, short* __restrict__ Kl,
    short* __restrict__ Vh, short* __restrict__ Vl)
{
    const int z = blockIdx.z;
    const float* bias = (z==0) ? bq : (z==1) ? bk : bv;
    short* outH       = (z==0) ? Qh : (z==1) ? Kh : Vh;
    short* outL       = (z==0) ? Ql : (z==1) ? Kl : Vl;
    const float scale = (z==0) ? 0.17677669529663687f : 1.0f;
    const short* bth = WTh + (size_t)z * 65536;
    const short* btl = WTl + (size_t)z * 65536;
    __shared__ __align__(16) short lds[2][16384];
    const int tid = threadIdx.x;
    const int lane = tid & 63, w = tid >> 6;
    const int g = lane >> 4, li = lane & 15;
    const int wr = w >> 2, wc = w & 3;
    const int m0 = blockIdx.x * 128, n0 = blockIdx.y * 128;
    const int sr = tid >> 2, sc = (tid & 3) * 8;
    const int wbase = w * 512;
    f32x4 acc[4][2];
    #pragma unroll
    for (int i = 0; i < 4; ++i)
        #pragma unroll
        for (int j = 0; j < 2; ++j) acc[i][j] = (f32x4){0.f,0.f,0.f,0.f};

    {
        size_t ga = (size_t)(m0 + sr)*256 + sc;
        size_t gb = (size_t)(n0 + sr)*256 + sc;
        gload16(xh + ga,  &lds[0][        wbase]);
        gload16(xl + ga,  &lds[0][ 4096 + wbase]);
        gload16(bth + gb, &lds[0][ 8192 + wbase]);
        gload16(btl + gb, &lds[0][12288 + wbase]);
    }
    __syncthreads();

    for (int k = 0; k < 8; ++k) {
        const int cur = k & 1;
        if (k < 7) {
            const int nb = cur ^ 1;
            int k0n = (k+1)*32;
            size_t ga = (size_t)(m0 + sr)*256 + k0n + sc;
            size_t gb = (size_t)(n0 + sr)*256 + k0n + sc;
            gload16(xh + ga,  &lds[nb][        wbase]);
            gload16(xl + ga,  &lds[nb][ 4096 + wbase]);
            gload16(bth + gb, &lds[nb][ 8192 + wbase]);
            gload16(btl + gb, &lds[nb][12288 + wbase]);
        }
        bf16x8 ah[4], al[4], bh[2], bl[2];
        #pragma unroll
        for (int i = 0; i < 4; ++i) {
            int row = wr*64 + i*16 + li;
            ah[i] = *(const bf16x8*)&lds[cur][       row*32 + g*8];
            al[i] = *(const bf16x8*)&lds[cur][4096 + row*32 + g*8];
        }
        #pragma unroll
        for (int j = 0; j < 2; ++j) {
            int row = wc*32 + j*16 + li;
            bh[j] = *(const bf16x8*)&lds[cur][ 8192 + row*32 + g*8];
            bl[j] = *(const bf16x8*)&lds[cur][12288 + row*32 + g*8];
        }
        #pragma unroll
        for (int i = 0; i < 4; ++i)
            #pragma unroll
            for (int j = 0; j < 2; ++j) {
                acc[i][j] = __builtin_amdgcn_mfma_f32_16x16x32_bf16(bh[j], ah[i], acc[i][j], 0,0,0);
                acc[i][j] = __builtin_amdgcn_mfma_f32_16x16x32_bf16(bl[j], ah[i], acc[i][j], 0,0,0);
                acc[i][j] = __builtin_amdgcn_mfma_f32_16x16x32_bf16(bh[j], al[i], acc[i][j], 0,0,0);
            }
        __syncthreads();
    }
    #pragma unroll
    for (int i = 0; i < 4; ++i) {
        int mrow = m0 + wr*64 + i*16 + li;
        int b = mrow >> 8, nn = mrow & 255;
        #pragma unroll
        for (int j = 0; j < 2; ++j) {
            int c0 = n0 + wc*32 + j*16 + g*4;
            int h = c0 >> 5, hd = c0 & 31;
            float4 bi = *(const float4*)(bias + c0);
            float v0 = (acc[i][j][0] + bi.x) * scale;
            float v1 = (acc[i][j][1] + bi.y) * scale;
            float v2 = (acc[i][j][2] + bi.z) * scale;
            float v3 = (acc[i][j][3] + bi.w) * scale;
            short h0,l0,h1,l1,h2,l2,h3,l3;
            split2(v0,h0,l0); split2(v1,h1,l1); split2(v2,h2,l2); split2(v3,h3,l3);
            uint2 hiq, loq;
            hiq.x = pack2(h0,h1); hiq.y = pack2(h2,h3);
            loq.x = pack2(l0,l1); loq.y = pack2(l2,l3);
            size_t idx = ((size_t)(b*Hg + h)*Ng + nn)*HDg + hd;
            *(uint2*)&outH[idx] = hiq;
            *(uint2*)&outL[idx] = loq;
        }
    }
}

// ---------------- K2: MFMA flash attention (r14 known-good structure) -------
__global__ __launch_bounds__(512, 4) void attn_mfma(
    const short* __restrict__ Qh, const short* __restrict__ Ql,
    const short* __restrict__ Kh, const short* __restrict__ Kl,
    const short* __restrict__ Vh, const short* __restrict__ Vl,
    const float* __restrict__ dist,
    short* __restrict__ AOh, short* __restrict__ AOl)
{
    __shared__ __align__(16) short Khi [2][32][40];
    __shared__ __align__(16) short Klo [2][32][40];
    __shared__ __align__(16) short Vthi[2][32][40];
    __shared__ __align__(16) short Vtlo[2][32][40];
    __shared__ __align__(16) short Phi [8][32][40];
    __shared__ __align__(16) short Plo [8][32][40];

    const int i0 = blockIdx.x;
    const int xcd = i0 & 7;
    const int m_  = i0 >> 3;
    const int h   = m_ & 7;
    const int b   = (m_ >> 3) * 8 + xcd;
    const int bh  = b * 8 + h;

    const int tid = threadIdx.x;
    const int w = tid >> 6;
    const int lane = tid & 63;
    const int g = lane >> 4;
    const int li = lane & 15;
    const int q0 = w * 32;
    const int skey = tid >> 4;
    const int se0  = (tid & 15) * 2;
    const float* dall = dist + (size_t)b*Ng*Ng;

    bf16x8 qh[2], ql[2];
    #pragma unroll
    for (int tq = 0; tq < 2; ++tq) {
        size_t qoff = ((size_t)bh * Ng + q0 + tq*16 + li) * HDg + g*8;
        qh[tq] = *(const bf16x8*)(Qh + qoff);
        ql[tq] = *(const bf16x8*)(Ql + qoff);
    }

    {
        size_t koff = ((size_t)bh*Ng + skey) * HDg + se0;
        unsigned kh1 = *(const unsigned*)(Kh + koff);
        unsigned kl1 = *(const unsigned*)(Kl + koff);
        unsigned vh1 = *(const unsigned*)(Vh + koff);
        unsigned vl1 = *(const unsigned*)(Vl + koff);
        *(unsigned*)&Khi[0][skey][se0] = kh1;
        *(unsigned*)&Klo[0][skey][se0] = kl1;
        Vthi[0][se0+0][skey] = (short)(vh1 & 0xffff);
        Vthi[0][se0+1][skey] = (short)(vh1 >> 16);
        Vtlo[0][se0+0][skey] = (short)(vl1 & 0xffff);
        Vtlo[0][se0+1][skey] = (short)(vl1 >> 16);
    }
    __syncthreads();

    f32x4 O[2][2];
    #pragma unroll
    for (int tq=0;tq<2;++tq)
        #pragma unroll
        for (int td=0;td<2;++td) O[tq][td] = (f32x4){0.f,0.f,0.f,0.f};
    float lpart[2] = {0.f, 0.f};

    for (int ch = 0; ch < 8; ++ch) {
        const int cur = ch & 1;
        const bool pref = (ch < 7);
        unsigned khr, klr, vhr, vlr;
        if (pref) {
            size_t koff = ((size_t)bh*Ng + (ch+1)*32 + skey) * HDg + se0;
            khr = *(const unsigned*)(Kh + koff);
            klr = *(const unsigned*)(Kl + koff);
            vhr = *(const unsigned*)(Vh + koff);
            vlr = *(const unsigned*)(Vl + koff);
        }
        f32x4 sacc[2][2];
        #pragma unroll
        for (int tq = 0; tq < 2; ++tq)
            #pragma unroll
            for (int tc = 0; tc < 2; ++tc) {
                const float* dp = dall + (size_t)(q0 + tq*16 + li)*Ng + ch*32 + tc*16 + g*4;
                float4 dv = *(const float4*)dp;
                sacc[tq][tc] = (f32x4){dv.x, dv.y, dv.z, dv.w};
            }
        bf16x8 kbh[2], kbl[2];
        #pragma unroll
        for (int tc = 0; tc < 2; ++tc) {
            kbh[tc] = *(const bf16x8*)&Khi[cur][tc*16+li][g*8];
            kbl[tc] = *(const bf16x8*)&Klo[cur][tc*16+li][g*8];
        }
        #pragma unroll
        for (int tq = 0; tq < 2; ++tq)
            #pragma unroll
            for (int tc = 0; tc < 2; ++tc) {
                sacc[tq][tc] = __builtin_amdgcn_mfma_f32_16x16x32_bf16(kbh[tc], qh[tq], sacc[tq][tc], 0,0,0);
                sacc[tq][tc] = __builtin_amdgcn_mfma_f32_16x16x32_bf16(kbl[tc], qh[tq], sacc[tq][tc], 0,0,0);
                sacc[tq][tc] = __builtin_amdgcn_mfma_f32_16x16x32_bf16(kbh[tc], ql[tq], sacc[tq][tc], 0,0,0);
            }
        #pragma unroll
        for (int tq = 0; tq < 2; ++tq)
            #pragma unroll
            for (int tc = 0; tc < 2; ++tc) {
                float p0 = __expf(sacc[tq][tc][0] - 16.f);
                float p1 = __expf(sacc[tq][tc][1] - 16.f);
                float p2 = __expf(sacc[tq][tc][2] - 16.f);
                float p3 = __expf(sacc[tq][tc][3] - 16.f);
                lpart[tq] += p0; lpart[tq] += p1; lpart[tq] += p2; lpart[tq] += p3;
                unsigned u0 = __float_as_uint(p0), u1 = __float_as_uint(p1);
                unsigned u2 = __float_as_uint(p2), u3 = __float_as_uint(p3);
                float r0 = p0 - __uint_as_float(u0 & 0xffff0000u);
                float r1 = p1 - __uint_as_float(u1 & 0xffff0000u);
                float r2 = p2 - __uint_as_float(u2 & 0xffff0000u);
                float r3 = p3 - __uint_as_float(u3 & 0xffff0000u);
                uint2 hiq, loq;
                hiq.x = (u0 >> 16) | (u1 & 0xffff0000u);
                hiq.y = (u2 >> 16) | (u3 & 0xffff0000u);
                loq.x = (__float_as_uint(r0) >> 16) | (__float_as_uint(r1) & 0xffff0000u);
                loq.y = (__float_as_uint(r2) >> 16) | (__float_as_uint(r3) & 0xffff0000u);
                *(uint2*)&Phi[w][tq*16 + li][tc*16 + g*4] = hiq;
                *(uint2*)&Plo[w][tq*16 + li][tc*16 + g*4] = loq;
            }
        bf16x8 vbh[2], vbl[2];
        #pragma unroll
        for (int td = 0; td < 2; ++td) {
            vbh[td] = *(const bf16x8*)&Vthi[cur][td*16+li][g*8];
            vbl[td] = *(const bf16x8*)&Vtlo[cur][td*16+li][g*8];
        }
        #pragma unroll
        for (int tq = 0; tq < 2; ++tq) {
            bf16x8 ph = *(const bf16x8*)&Phi[w][tq*16+li][g*8];
            bf16x8 pl = *(const bf16x8*)&Plo[w][tq*16+li][g*8];
            #pragma unroll
            for (int td = 0; td < 2; ++td) {
                O[tq][td] = __builtin_amdgcn_mfma_f32_16x16x32_bf16(vbh[td], ph, O[tq][td], 0,0,0);
                O[tq][td] = __builtin_amdgcn_mfma_f32_16x16x32_bf16(vbl[td], ph, O[tq][td], 0,0,0);
                O[tq][td] = __builtin_amdgcn_mfma_f32_16x16x32_bf16(vbh[td], pl, O[tq][td], 0,0,0);
            }
        }
        if (pref) {
            const int nb = cur ^ 1;
            *(unsigned*)&Khi[nb][skey][se0] = khr;
            *(unsigned*)&Klo[nb][skey][se0] = klr;
            Vthi[nb][se0+0][skey] = (short)(vhr & 0xffff);
            Vthi[nb][se0+1][skey] = (short)(vhr >> 16);
            Vtlo[nb][se0+0][skey] = (short)(vlr & 0xffff);
            Vtlo[nb][se0+1][skey] = (short)(vlr >> 16);
        }
        __syncthreads();
    }
    float inv[2];
    #pragma unroll
    for (int tq = 0; tq < 2; ++tq) {
        float s = lpart[tq];
        s += __shfl_xor(s, 16);
        s += __shfl_xor(s, 32);
        inv[tq] = 1.f / s;
    }
    #pragma unroll
    for (int tq = 0; tq < 2; ++tq)
        #pragma unroll
        for (int td = 0; td < 2; ++td) {
            float v0 = O[tq][td][0] * inv[tq];
            float v1 = O[tq][td][1] * inv[tq];
            float v2 = O[tq][td][2] * inv[tq];
            float v3 = O[tq][td][3] * inv[tq];
            unsigned u0 = __float_as_uint(v0), u1 = __float_as_uint(v1);
            unsigned u2 = __float_as_uint(v2), u3 = __float_as_uint(v3);
            float r0 = v0 - __uint_as_float(u0 & 0xffff0000u);
            float r1 = v1 - __uint_as_float(u1 & 0xffff0000u);
            float r2 = v2 - __uint_as_float(u2 & 0xffff0000u);
            float r3 = v3 - __uint_as_float(u3 & 0xffff0000u);
            uint2 hiq, loq;
            hiq.x = (u0 >> 16) | (u1 & 0xffff0000u);
            hiq.y = (u2 >> 16) | (u3 & 0xffff0000u);
            loq.x = (__float_as_uint(r0) >> 16) | (__float_as_uint(r1) & 0xffff0000u);
            loq.y = (__float_as_uint(r2) >> 16) | (__float_as_uint(r3) & 0xffff0000u);
            int q = q0 + tq*16 + li;
            size_t base = ((size_t)b*Ng + q)*Dg + h*HDg + td*16 + g*4;
            *(uint2*)&AOh[base] = hiq;
            *(uint2*)&AOl[base] = loq;
        }
}

// ---------------- K3: output projection + fused pooling-score partials ------
__global__ __launch_bounds__(512, 4) void out_mm(
    const short* __restrict__ aoh, const short* __restrict__ aol,
    const short* __restrict__ bth, const short* __restrict__ btl,
    const float* __restrict__ bo, const float* __restrict__ pw,
    float* __restrict__ enc, float* __restrict__ score_part)
{
    __shared__ __align__(16) short lds[2][16384];
    const int tid = threadIdx.x;
    const int lane = tid & 63, w = tid >> 6;
    const int g = lane >> 4, li = lane & 15;
    const int wr = w >> 2, wc = w & 3;
    const int m0 = blockIdx.x * 128, n0 = blockIdx.y * 128;
    const int sr = tid >> 2, sc = (tid & 3) * 8;
    const int wbase = w * 512;
    f32x4 acc[4][2];
    #pragma unroll
    for (int i = 0; i < 4; ++i)
        #pragma unroll
        for (int j = 0; j < 2; ++j) acc[i][j] = (f32x4){0.f,0.f,0.f,0.f};

    {
        size_t ga = (size_t)(m0 + sr)*256 + sc;
        size_t gb = (size_t)(n0 + sr)*256 + sc;
        gload16(aoh + ga, &lds[0][        wbase]);
        gload16(aol + ga, &lds[0][ 4096 + wbase]);
        gload16(bth + gb, &lds[0][ 8192 + wbase]);
        gload16(btl + gb, &lds[0][12288 + wbase]);
    }
    __syncthreads();

    for (int k = 0; k < 8; ++k) {
        const int cur = k & 1;
        if (k < 7) {
            const int nb = cur ^ 1;
            int k0n = (k+1)*32;
            size_t ga = (size_t)(m0 + sr)*256 + k0n + sc;
            size_t gb = (size_t)(n0 + sr)*256 + k0n + sc;
            gload16(aoh + ga, &lds[nb][        wbase]);
            gload16(aol + ga, &lds[nb][ 4096 + wbase]);
            gload16(bth + gb, &lds[nb][ 8192 + wbase]);
            gload16(btl + gb, &lds[nb][12288 + wbase]);
        }
        bf16x8 ah[4], al[4], bh[2], bl[2];
        #pragma unroll
        for (int i = 0; i < 4; ++i) {
            int row = wr*64 + i*16 + li;
            ah[i] = *(const bf16x8*)&lds[cur][       row*32 + g*8];
            al[i] = *(const bf16x8*)&lds[cur][4096 + row*32 + g*8];
        }
        #pragma unroll
        for (int j = 0; j < 2; ++j) {
            int row = wc*32 + j*16 + li;
            bh[j] = *(const bf16x8*)&lds[cur][ 8192 + row*32 + g*8];
            bl[j] = *(const bf16x8*)&lds[cur][12288 + row*32 + g*8];
        }
        #pragma unroll
        for (int i = 0; i < 4; ++i)
            #pragma unroll
            for (int j = 0; j < 2; ++j) {
                acc[i][j] = __builtin_amdgcn_mfma_f32_16x16x32_bf16(bh[j], ah[i], acc[i][j], 0,0,0);
                acc[i][j] = __builtin_amdgcn_mfma_f32_16x16x32_bf16(bl[j], ah[i], acc[i][j], 0,0,0);
                acc[i][j] = __builtin_amdgcn_mfma_f32_16x16x32_bf16(bh[j], al[i], acc[i][j], 0,0,0);
            }
        __syncthreads();
    }
    const int pslot = blockIdx.y * 4 + wc;
    #pragma unroll
    for (int i = 0; i < 4; ++i) {
        int mrow = m0 + wr*64 + i*16 + li;
        float s = 0.f;
        #pragma unroll
        for (int j = 0; j < 2; ++j) {
            int c0 = n0 + wc*32 + j*16 + g*4;
            float4 bo4 = *(const float4*)(bo + c0);
            float4 pw4 = *(const float4*)(pw + c0);
            float4 v;
            v.x = acc[i][j][0] + bo4.x;
            v.y = acc[i][j][1] + bo4.y;
            v.z = acc[i][j][2] + bo4.z;
            v.w = acc[i][j][3] + bo4.w;
            *(float4*)&enc[(size_t)mrow*Dg + c0] = v;
            s += v.x*pw4.x + v.y*pw4.y + v.z*pw4.z + v.w*pw4.w;
        }
        s += __shfl_xor(s, 16);
        s += __shfl_xor(s, 32);
        if (g == 0) score_part[(size_t)pslot * BNg + mrow] = s;
    }
}

// ---------------- norm ----------------
__global__ void norm_kernel(const float* __restrict__ pw, float* __restrict__ inv_norm)
{
    int t = threadIdx.x;
    float s = 0.f;
    for (int d = t; d < Dg; d += 64) s = fmaf(pw[d], pw[d], s);
    #pragma unroll
    for (int off = 32; off > 0; off >>= 1) s += __shfl_xor(s, off);
    if (t == 0) *inv_norm = 1.0f / sqrtf(s);
}

// ---------------- K5: per-graph exact top-K via rank count ----------------
__global__ __launch_bounds__(256) void topk_kernel(
    const float* __restrict__ score_part, float* __restrict__ vals, int* __restrict__ idxs,
    int* __restrict__ new_id, float* __restrict__ out_batch)
{
    __shared__ float sh[Ng];
    int bgr = blockIdx.x, t = threadIdx.x;
    int row = bgr * Ng + t;
    float mine = 0.f;
    #pragma unroll
    for (int p = 0; p < 8; ++p) mine += score_part[(size_t)p * BNg + row];
    sh[t] = mine;
    __syncthreads();
    int cnt = 0;
    for (int j = 0; j < Ng; ++j) {
        float v = sh[j];
        cnt += (v > mine || (v == mine && j < t)) ? 1 : 0;
    }
    if (cnt < Kg) {
        int pos = bgr * Kg + cnt;
        vals[pos] = mine;
        idxs[pos] = t;
        new_id[bgr * Ng + t] = pos;
        out_batch[pos] = (float)bgr;
    } else {
        new_id[bgr * Ng + t] = SENT;
    }
}

// ---------------- K6: gather + tanh scale ----------------
__global__ __launch_bounds__(256) void subx_kernel(
    const float* __restrict__ enc, const float* __restrict__ vals,
    const int* __restrict__ idxs, const float* __restrict__ inv_norm,
    float* __restrict__ out_subx)
{
    int j    = blockIdx.x * 4 + (threadIdx.x >> 6);
    int lane = threadIdx.x & 63;
    int bgr  = j >> 7;
    int src  = bgr * Ng + idxs[j];
    float scale = tanhf(vals[j] * (*inv_norm));
    float4 v = reinterpret_cast<const float4*>(enc + (size_t)src * Dg)[lane];
    v.x *= scale; v.y *= scale; v.z *= scale; v.w *= scale;
    reinterpret_cast<float4*>(out_subx + (size_t)j * Dg)[lane] = v;
}

// ---------------- edge pipeline ----------------
__global__ __launch_bounds__(256) void edge_hist(
    const int* __restrict__ ei, const int* __restrict__ new_id, int* __restrict__ counts)
{
    int e = blockIdx.x * 256 + threadIdx.x;
    int r = new_id[ei[e]];
    int c = new_id[ei[Eg + e]];
    if (r != SENT && c != SENT) atomicAdd(&counts[r], 1);
}

__global__ __launch_bounds__(256) void scan_kernel(
    const int* __restrict__ counts, int* __restrict__ offsets)
{
    __shared__ int sums[256];
    int t = threadIdx.x;
    int base = t * 64;
    int s = 0;
    for (int i = 0; i < 64; ++i) s += counts[base + i];
    sums[t] = s;
    __syncthreads();
    for (int off = 1; off < 256; off <<= 1) {
        int add = (t >= off) ? sums[t - off] : 0;
        __syncthreads();
        sums[t] += add;
        __syncthreads();
    }
    int run = sums[t] - s;
    for (int i = 0; i < 64; ++i) { offsets[base + i] = run; run += counts[base + i]; }
    if (t == 255) offsets[SENT] = run;
}

__global__ __launch_bounds__(256) void edge_scatter(
    const int* __restrict__ ei, const int* __restrict__ new_id,
    const int* __restrict__ offsets, int* __restrict__ cursor, int* __restrict__ bucket)
{
    int e = blockIdx.x * 256 + threadIdx.x;
    int r = new_id[ei[e]];
    int c = new_id[ei[Eg + e]];
    if (r != SENT && c != SENT) {
        int pos = offsets[r] + atomicAdd(&cursor[r], 1);
        bucket[pos] = c;
    }
}

__global__ __launch_bounds__(256) void edge_sort_emit(
    const int* __restrict__ offsets, int* bucket, float* __restrict__ out_edges)
{
    int r = blockIdx.x * 256 + threadIdx.x;
    int s = offsets[r], e = offsets[r + 1];
    for (int i = s + 1; i < e; ++i) {
        int key = bucket[i];
        int j = i - 1;
        while (j >= s && bucket[j] > key) { bucket[j+1] = bucket[j]; --j; }
        bucket[j+1] = key;
    }
    float rf = (float)r;
    for (int i = s; i < e; ++i) {
        out_edges[i]      = rf;
        out_edges[Eg + i] = (float)bucket[i];
    }
}

__global__ __launch_bounds__(256) void edge_fill(
    const int* __restrict__ offsets, float* __restrict__ out_edges)
{
    int p = blockIdx.x * 256 + threadIdx.x;
    if (p >= offsets[SENT]) {
        out_edges[p]      = (float)SENT;
        out_edges[Eg + p] = (float)SENT;
    }
}

// ---------------- launch ----------------
extern "C" void kernel_launch(void* const* d_in, const int* in_sizes, int n_in,
                              void* d_out, int out_size, void* d_ws, size_t ws_size,
                              hipStream_t stream)
{
    const float* x    = (const float*)d_in[0];
    const float* dist = (const float*)d_in[2];
    const int*   ei   = (const int*)d_in[3];
    const float* Wq = (const float*)d_in[5];
    const float* bq = (const float*)d_in[6];
    const float* Wk = (const float*)d_in[7];
    const float* bk = (const float*)d_in[8];
    const float* Wv = (const float*)d_in[9];
    const float* bv = (const float*)d_in[10];
    const float* Wo = (const float*)d_in[11];
    const float* bo = (const float*)d_in[12];
    const float* pw = (const float*)d_in[13];

    float* out       = (float*)d_out;
    float* enc_out   = out;                     // [B*N*D]
    float* subx_out  = out + 8388608;           // [B*K*D]
    float* edge_out  = out + 12582912;          // [2*E]
    float* batch_out = out + 13631488;          // [B*K]

    float* ws      = (float*)d_ws;
    short* Qh      = (short*)ws;                 // 8,388,608 shorts each
    short* Ql      = (short*)(ws + 4194304);
    short* Kh      = (short*)(ws + 8388608);
    short* Kl      = (short*)(ws + 12582912);
    short* Vh      = (short*)(ws + 16777216);
    short* Vl      = (short*)(ws + 20971520);
    short* xh      = (short*)(ws + 25165824);    // 8,388,608 shorts
    short* xl      = (short*)(ws + 29360128);
    short* AOh     = xh;                         // alias after split_x consumed
    short* AOl     = xl;
    short* WTh     = (short*)(ws + 33554432);    // 4*65536 shorts
    short* WTl     = (short*)(ws + 33685504);
    float* vals    = ws + 33849344;              // 16384
    int*   idxs    = (int*)(ws + 33865728);      // 16384
    int*   new_id  = (int*)(ws + 33882112);      // 32768
    int*   counts  = (int*)(ws + 33914880);      // 16384
    int*   offsets = (int*)(ws + 33931264);      // 16416
    int*   cursor  = (int*)(ws + 33947680);      // 16384
    float* inv_nm  = ws + 33964064;              // 32
    int*   bucket  = (int*)(ws + 33964096);      // 524288
    float* score_part = ws + 34488384;           // 8*32768 = 262144

    hipMemsetAsync(counts, 0, SENT * sizeof(int), stream);
    hipMemsetAsync(cursor, 0, SENT * sizeof(int), stream);

    split_x       <<<dim3(4096),               256, 0, stream>>>(x, xh, xl);
    wprep         <<<dim3(64),                 256, 0, stream>>>(Wq, Wk, Wv, Wo, WTh, WTl);
    norm_kernel   <<<dim3(1),                   64, 0, stream>>>(pw, inv_nm);
    qkv_mm        <<<dim3(BNg/128, Dg/128, 3), 512, 0, stream>>>(xh, xl, WTh, WTl, bq, bk, bv,
                                                                 Qh, Ql, Kh, Kl, Vh, Vl);
    attn_mfma     <<<dim3(Bg*Hg),              512, 0, stream>>>(Qh, Ql, Kh, Kl, Vh, Vl, dist, AOh, AOl);
    out_mm        <<<dim3(BNg/128, Dg/128),    512, 0, stream>>>(AOh, AOl, WTh + 3*65536, WTl + 3*65536,
                                                                 bo, pw, enc_out, score_part);
    topk_kernel   <<<dim3(Bg),                 256, 0, stream>>>(score_part, vals, idxs, new_id, batch_out);
    subx_kernel   <<<dim3((Bg*Kg)/4),          256, 0, stream>>>(enc_out, vals, idxs, inv_nm, subx_out);
    edge_hist     <<<dim3(Eg/256),             256, 0, stream>>>(ei, new_id, counts);
    scan_kernel   <<<dim3(1),                  256, 0, stream>>>(counts, offsets);
    edge_scatter  <<<dim3(Eg/256),             256, 0, stream>>>(ei, new_id, offsets, cursor, bucket);
    edge_sort_emit<<<dim3(SENT/256),           256, 0, stream>>>(offsets, bucket, edge_out);
    edge_fill     <<<dim3(Eg/256),             256, 0, stream>>>(offsets, edge_out);
    (void)in_sizes; (void)n_in; (void)out_size; (void)ws_size;
}

// Round 17
// 218.537 us; speedup vs baseline: 1.2666x; 1.0106x over previous
//
#include <hip/hip_runtime.h>
#include <math.h>

#define Bg   128
#define Ng   256
#define Dg   256
#define Hg   8
#define HDg  32
#define Eg   524288
#define Kg   128
#define BNg  32768
#define SENT 16384   // = Bg*Kg

using bf16x8 = __attribute__((ext_vector_type(8))) short;
using f32x4  = __attribute__((ext_vector_type(4))) float;

// split f32 -> bf16 hi (truncated) + bf16 lo (residual)
__device__ inline void split2(float x, short &h, short &l) {
    unsigned u = __float_as_uint(x);
    h = (short)(u >> 16);
    float hf = __uint_as_float(u & 0xffff0000u);
    float r = x - hf;
    l = (short)(__float_as_uint(r) >> 16);
}
__device__ inline unsigned pack2(short a, short b) {
    return (unsigned)(unsigned short)a | ((unsigned)(unsigned short)b << 16);
}
// async global->LDS, 16B per lane; dst is the WAVE-UNIFORM base (lane*16B added by HW)
__device__ inline void gload16(const void* g, void* l) {
    __builtin_amdgcn_global_load_lds(
        (const __attribute__((address_space(1))) unsigned*)g,
        (__attribute__((address_space(3))) unsigned*)l, 16, 0, 0);
}

// ---------------- P1: split x into hi/lo bf16 ----------------
__global__ __launch_bounds__(256) void split_x(
    const float* __restrict__ x, short* __restrict__ xh, short* __restrict__ xl)
{
    size_t i = ((size_t)blockIdx.x * 256 + threadIdx.x) * 8;
    float4 a = *(const float4*)(x + i);
    float4 b = *(const float4*)(x + i + 4);
    float v[8] = {a.x,a.y,a.z,a.w,b.x,b.y,b.z,b.w};
    short h[8], l[8];
    #pragma unroll
    for (int j = 0; j < 8; ++j) split2(v[j], h[j], l[j]);
    uint4 uh, ul;
    uh.x = pack2(h[0],h[1]); uh.y = pack2(h[2],h[3]);
    uh.z = pack2(h[4],h[5]); uh.w = pack2(h[6],h[7]);
    ul.x = pack2(l[0],l[1]); ul.y = pack2(l[2],l[3]);
    ul.z = pack2(l[4],l[5]); ul.w = pack2(l[6],l[7]);
    *(uint4*)(xh + i) = uh;
    *(uint4*)(xl + i) = ul;
}

// ---------------- P2: transpose + split weights: WT[n][k] = W[k][n] ----------
__global__ __launch_bounds__(256) void wprep(
    const float* __restrict__ Wq, const float* __restrict__ Wk,
    const float* __restrict__ Wv, const float* __restrict__ Wo,
    short* __restrict__ WTh, short* __restrict__ WTl)
{
    __shared__ float t[64][65];
    const int bid = blockIdx.x;          // 0..63
    const int mat = bid >> 4;
    const int kt = (bid >> 2) & 3, nt = bid & 3;
    const float* W = (mat==0) ? Wq : (mat==1) ? Wk : (mat==2) ? Wv : Wo;
    const int tid = threadIdx.x;
    const int r = tid >> 2, c4 = tid & 3;
    #pragma unroll
    for (int i = 0; i < 4; ++i) {
        float4 v = *(const float4*)(W + (size_t)(kt*64 + r)*256 + nt*64 + c4*16 + i*4);
        t[r][c4*16 + i*4 + 0] = v.x; t[r][c4*16 + i*4 + 1] = v.y;
        t[r][c4*16 + i*4 + 2] = v.z; t[r][c4*16 + i*4 + 3] = v.w;
    }
    __syncthreads();
    const int n = r, k0 = c4 * 16;
    short hb[16], lb[16];
    #pragma unroll
    for (int i = 0; i < 16; ++i) split2(t[k0 + i][n], hb[i], lb[i]);
    size_t base = (size_t)mat*65536 + (size_t)(nt*64 + n)*256 + kt*64 + k0;
    uint4 uh0, uh1, ul0, ul1;
    uh0.x=pack2(hb[0],hb[1]);  uh0.y=pack2(hb[2],hb[3]);  uh0.z=pack2(hb[4],hb[5]);  uh0.w=pack2(hb[6],hb[7]);
    uh1.x=pack2(hb[8],hb[9]);  uh1.y=pack2(hb[10],hb[11]);uh1.z=pack2(hb[12],hb[13]);uh1.w=pack2(hb[14],hb[15]);
    ul0.x=pack2(lb[0],lb[1]);  ul0.y=pack2(lb[2],lb[3]);  ul0.z=pack2(lb[4],lb[5]);  ul0.w=pack2(lb[6],lb[7]);
    ul1.x=pack2(lb[8],lb[9]);  ul1.y=pack2(lb[10],lb[11]);ul1.z=pack2(lb[12],lb[13]);ul1.w=pack2(lb[14],lb[15]);
    *(uint4*)&WTh[base]     = uh0; *(uint4*)&WTh[base + 8] = uh1;
    *(uint4*)&WTl[base]     = ul0; *(uint4*)&WTl[base + 8] = ul1;
}

// ---------------- K1: QKV projection, 8-wave, 3-term, async-LDS dbuf --------
__global__ __launch_bounds__(512, 4) void qkv_mm(
    const short* __restrict__ xh, const short* __restrict__ xl,
    const short* __restrict__ WTh, const short* __restrict__ WTl,
    const float* __restrict__ bq, const float* __restrict__ bk, const float* __restrict__ bv,
    short* __restrict__ Qh, short* __restrict__ Ql,
    short* __restrict__ Kh, short* __restrict__ Kl,
    short* __restrict__ Vh, short* __restrict__ Vl)
{
    const int z = blockIdx.z;
    const float* bias = (z==0) ? bq : (z==1) ? bk : bv;
    short* outH       = (z==0) ? Qh : (z==1) ? Kh : Vh;
    short* outL       = (z==0) ? Ql : (z==1) ? Kl : Vl;
    const float scale = (z==0) ? 0.17677669529663687f : 1.0f;
    const short* bth = WTh + (size_t)z * 65536;
    const short* btl = WTl + (size_t)z * 65536;
    __shared__ __align__(16) short lds[2][16384];
    const int tid = threadIdx.x;
    const int lane = tid & 63, w = tid >> 6;
    const int g = lane >> 4, li = lane & 15;
    const int wr = w >> 2, wc = w & 3;
    const int m0 = blockIdx.x * 128, n0 = blockIdx.y * 128;
    const int sr = tid >> 2, sc = (tid & 3) * 8;
    const int wbase = w * 512;
    f32x4 acc[4][2];
    #pragma unroll
    for (int i = 0; i < 4; ++i)
        #pragma unroll
        for (int j = 0; j < 2; ++j) acc[i][j] = (f32x4){0.f,0.f,0.f,0.f};

    {
        size_t ga = (size_t)(m0 + sr)*256 + sc;
        size_t gb = (size_t)(n0 + sr)*256 + sc;
        gload16(xh + ga,  &lds[0][        wbase]);
        gload16(xl + ga,  &lds[0][ 4096 + wbase]);
        gload16(bth + gb, &lds[0][ 8192 + wbase]);
        gload16(btl + gb, &lds[0][12288 + wbase]);
    }
    __syncthreads();

    for (int k = 0; k < 8; ++k) {
        const int cur = k & 1;
        if (k < 7) {
            const int nb = cur ^ 1;
            int k0n = (k+1)*32;
            size_t ga = (size_t)(m0 + sr)*256 + k0n + sc;
            size_t gb = (size_t)(n0 + sr)*256 + k0n + sc;
            gload16(xh + ga,  &lds[nb][        wbase]);
            gload16(xl + ga,  &lds[nb][ 4096 + wbase]);
            gload16(bth + gb, &lds[nb][ 8192 + wbase]);
            gload16(btl + gb, &lds[nb][12288 + wbase]);
        }
        bf16x8 ah[4], al[4], bh[2], bl[2];
        #pragma unroll
        for (int i = 0; i < 4; ++i) {
            int row = wr*64 + i*16 + li;
            ah[i] = *(const bf16x8*)&lds[cur][       row*32 + g*8];
            al[i] = *(const bf16x8*)&lds[cur][4096 + row*32 + g*8];
        }
        #pragma unroll
        for (int j = 0; j < 2; ++j) {
            int row = wc*32 + j*16 + li;
            bh[j] = *(const bf16x8*)&lds[cur][ 8192 + row*32 + g*8];
            bl[j] = *(const bf16x8*)&lds[cur][12288 + row*32 + g*8];
        }
        #pragma unroll
        for (int i = 0; i < 4; ++i)
            #pragma unroll
            for (int j = 0; j < 2; ++j) {
                acc[i][j] = __builtin_amdgcn_mfma_f32_16x16x32_bf16(bh[j], ah[i], acc[i][j], 0,0,0);
                acc[i][j] = __builtin_amdgcn_mfma_f32_16x16x32_bf16(bl[j], ah[i], acc[i][j], 0,0,0);
                acc[i][j] = __builtin_amdgcn_mfma_f32_16x16x32_bf16(bh[j], al[i], acc[i][j], 0,0,0);
            }
        __syncthreads();
    }
    #pragma unroll
    for (int i = 0; i < 4; ++i) {
        int mrow = m0 + wr*64 + i*16 + li;
        int b = mrow >> 8, nn = mrow & 255;
        #pragma unroll
        for (int j = 0; j < 2; ++j) {
            int c0 = n0 + wc*32 + j*16 + g*4;
            int h = c0 >> 5, hd = c0 & 31;
            float4 bi = *(const float4*)(bias + c0);
            float v0 = (acc[i][j][0] + bi.x) * scale;
            float v1 = (acc[i][j][1] + bi.y) * scale;
            float v2 = (acc[i][j][2] + bi.z) * scale;
            float v3 = (acc[i][j][3] + bi.w) * scale;
            short h0,l0,h1,l1,h2,l2,h3,l3;
            split2(v0,h0,l0); split2(v1,h1,l1); split2(v2,h2,l2); split2(v3,h3,l3);
            uint2 hiq, loq;
            hiq.x = pack2(h0,h1); hiq.y = pack2(h2,h3);
            loq.x = pack2(l0,l1); loq.y = pack2(l2,l3);
            size_t idx = ((size_t)(b*Hg + h)*Ng + nn)*HDg + hd;
            *(uint2*)&outH[idx] = hiq;
            *(uint2*)&outL[idx] = loq;
        }
    }
}

// ---------------- K2: MFMA flash attention (named-register dist prefetch) ----
// One chunk of look-ahead for dist (C-seeds) AND K/V, all in NAMED registers
// (no arrays/lambdas -> no scratch). Bit-identical arithmetic to r16.
#define ATTN_CHUNK(CH, D00,D01,D10,D11, N00,N01,N10,N11)                         \
  {                                                                              \
    const int cur = (CH) & 1;                                                    \
    unsigned khr=0u, klr=0u, vhr=0u, vlr=0u;                                     \
    if ((CH) < 7) {                                                              \
        const float* dbase = dall + ((CH)+1)*32;                                 \
        N00 = *(const float4*)(dbase + (size_t)(q0 +  0 + li)*Ng +  0 + g*4);    \
        N01 = *(const float4*)(dbase + (size_t)(q0 +  0 + li)*Ng + 16 + g*4);    \
        N10 = *(const float4*)(dbase + (size_t)(q0 + 16 + li)*Ng +  0 + g*4);    \
        N11 = *(const float4*)(dbase + (size_t)(q0 + 16 + li)*Ng + 16 + g*4);    \
        size_t koff = ((size_t)bh*Ng + ((CH)+1)*32 + skey) * HDg + se0;          \
        khr = *(const unsigned*)(Kh + koff);                                     \
        klr = *(const unsigned*)(Kl + koff);                                     \
        vhr = *(const unsigned*)(Vh + koff);                                     \
        vlr = *(const unsigned*)(Vl + koff);                                     \
    }                                                                            \
    f32x4 sacc[2][2];                                                            \
    sacc[0][0] = (f32x4){D00.x, D00.y, D00.z, D00.w};                            \
    sacc[0][1] = (f32x4){D01.x, D01.y, D01.z, D01.w};                            \
    sacc[1][0] = (f32x4){D10.x, D10.y, D10.z, D10.w};                            \
    sacc[1][1] = (f32x4){D11.x, D11.y, D11.z, D11.w};                            \
    bf16x8 kbh[2], kbl[2];                                                       \
    _Pragma("unroll")                                                            \
    for (int tc = 0; tc < 2; ++tc) {                                             \
        kbh[tc] = *(const bf16x8*)&Khi[cur][tc*16+li][g*8];                      \
        kbl[tc] = *(const bf16x8*)&Klo[cur][tc*16+li][g*8];                      \
    }                                                                            \
    _Pragma("unroll")                                                            \
    for (int tq = 0; tq < 2; ++tq)                                               \
        _Pragma("unroll")                                                        \
        for (int tc = 0; tc < 2; ++tc) {                                         \
            sacc[tq][tc] = __builtin_amdgcn_mfma_f32_16x16x32_bf16(kbh[tc], qh[tq], sacc[tq][tc], 0,0,0); \
            sacc[tq][tc] = __builtin_amdgcn_mfma_f32_16x16x32_bf16(kbl[tc], qh[tq], sacc[tq][tc], 0,0,0); \
            sacc[tq][tc] = __builtin_amdgcn_mfma_f32_16x16x32_bf16(kbh[tc], ql[tq], sacc[tq][tc], 0,0,0); \
        }                                                                        \
    _Pragma("unroll")                                                            \
    for (int tq = 0; tq < 2; ++tq)                                               \
        _Pragma("unroll")                                                        \
        for (int tc = 0; tc < 2; ++tc) {                                         \
            float p0 = __expf(sacc[tq][tc][0] - 16.f);                           \
            float p1 = __expf(sacc[tq][tc][1] - 16.f);                           \
            float p2 = __expf(sacc[tq][tc][2] - 16.f);                           \
            float p3 = __expf(sacc[tq][tc][3] - 16.f);                           \
            lpart[tq] += p0; lpart[tq] += p1; lpart[tq] += p2; lpart[tq] += p3;  \
            unsigned u0 = __float_as_uint(p0), u1 = __float_as_uint(p1);         \
            unsigned u2 = __float_as_uint(p2), u3 = __float_as_uint(p3);         \
            float r0 = p0 - __uint_as_float(u0 & 0xffff0000u);                   \
            float r1 = p1 - __uint_as_float(u1 & 0xffff0000u);                   \
            float r2 = p2 - __uint_as_float(u2 & 0xffff0000u);                   \
            float r3 = p3 - __uint_as_float(u3 & 0xffff0000u);                   \
            uint2 hiq, loq;                                                      \
            hiq.x = (u0 >> 16) | (u1 & 0xffff0000u);                             \
            hiq.y = (u2 >> 16) | (u3 & 0xffff0000u);                             \
            loq.x = (__float_as_uint(r0) >> 16) | (__float_as_uint(r1) & 0xffff0000u); \
            loq.y = (__float_as_uint(r2) >> 16) | (__float_as_uint(r3) & 0xffff0000u); \
            *(uint2*)&Phi[w][tq*16 + li][tc*16 + g*4] = hiq;                     \
            *(uint2*)&Plo[w][tq*16 + li][tc*16 + g*4] = loq;                     \
        }                                                                        \
    bf16x8 vbh[2], vbl[2];                                                       \
    _Pragma("unroll")                                                            \
    for (int td = 0; td < 2; ++td) {                                             \
        vbh[td] = *(const bf16x8*)&Vthi[cur][td*16+li][g*8];                     \
        vbl[td] = *(const bf16x8*)&Vtlo[cur][td*16+li][g*8];                     \
    }                                                                            \
    _Pragma("unroll")                                                            \
    for (int tq = 0; tq < 2; ++tq) {                                             \
        bf16x8 ph = *(const bf16x8*)&Phi[w][tq*16+li][g*8];                      \
        bf16x8 pl = *(const bf16x8*)&Plo[w][tq*16+li][g*8];                      \
        _Pragma("unroll")                                                        \
        for (int td = 0; td < 2; ++td) {                                         \
            O[tq][td] = __builtin_amdgcn_mfma_f32_16x16x32_bf16(vbh[td], ph, O[tq][td], 0,0,0); \
            O[tq][td] = __builtin_amdgcn_mfma_f32_16x16x32_bf16(vbl[td], ph, O[tq][td], 0,0,0); \
            O[tq][td] = __builtin_amdgcn_mfma_f32_16x16x32_bf16(vbh[td], pl, O[tq][td], 0,0,0); \
        }                                                                        \
    }                                                                            \
    if ((CH) < 7) {                                                              \
        const int nb = cur ^ 1;                                                  \
        *(unsigned*)&Khi[nb][skey][se0] = khr;                                   \
        *(unsigned*)&Klo[nb][skey][se0] = klr;                                   \
        Vthi[nb][se0+0][skey] = (short)(vhr & 0xffff);                           \
        Vthi[nb][se0+1][skey] = (short)(vhr >> 16);                              \
        Vtlo[nb][se0+0][skey] = (short)(vlr & 0xffff);                           \
        Vtlo[nb][se0+1][skey] = (short)(vlr >> 16);                              \
    }                                                                            \
    __syncthreads();                                                             \
  }

__global__ __launch_bounds__(512, 4) void attn_mfma(
    const short* __restrict__ Qh, const short* __restrict__ Ql,
    const short* __restrict__ Kh, const short* __restrict__ Kl,
    const short* __restrict__ Vh, const short* __restrict__ Vl,
    const float* __restrict__ dist,
    short* __restrict__ AOh, short* __restrict__ AOl)
{
    __shared__ __align__(16) short Khi [2][32][40];
    __shared__ __align__(16) short Klo [2][32][40];
    __shared__ __align__(16) short Vthi[2][32][40];
    __shared__ __align__(16) short Vtlo[2][32][40];
    __shared__ __align__(16) short Phi [8][32][40];
    __shared__ __align__(16) short Plo [8][32][40];

    const int i0 = blockIdx.x;
    const int xcd = i0 & 7;
    const int m_  = i0 >> 3;
    const int h   = m_ & 7;
    const int b   = (m_ >> 3) * 8 + xcd;
    const int bh  = b * 8 + h;

    const int tid = threadIdx.x;
    const int w = tid >> 6;
    const int lane = tid & 63;
    const int g = lane >> 4;
    const int li = lane & 15;
    const int q0 = w * 32;
    const int skey = tid >> 4;
    const int se0  = (tid & 15) * 2;
    const float* dall = dist + (size_t)b*Ng*Ng;

    bf16x8 qh[2], ql[2];
    #pragma unroll
    for (int tq = 0; tq < 2; ++tq) {
        size_t qoff = ((size_t)bh * Ng + q0 + tq*16 + li) * HDg + g*8;
        qh[tq] = *(const bf16x8*)(Qh + qoff);
        ql[tq] = *(const bf16x8*)(Ql + qoff);
    }

    // prologue: dist chunk 0 -> named regs; K/V chunk 0 -> buf 0
    float4 dc00, dc01, dc10, dc11, dn00, dn01, dn10, dn11;
    dc00 = *(const float4*)(dall + (size_t)(q0 +  0 + li)*Ng +  0 + g*4);
    dc01 = *(const float4*)(dall + (size_t)(q0 +  0 + li)*Ng + 16 + g*4);
    dc10 = *(const float4*)(dall + (size_t)(q0 + 16 + li)*Ng +  0 + g*4);
    dc11 = *(const float4*)(dall + (size_t)(q0 + 16 + li)*Ng + 16 + g*4);
    {
        size_t koff = ((size_t)bh*Ng + skey) * HDg + se0;
        unsigned kh1 = *(const unsigned*)(Kh + koff);
        unsigned kl1 = *(const unsigned*)(Kl + koff);
        unsigned vh1 = *(const unsigned*)(Vh + koff);
        unsigned vl1 = *(const unsigned*)(Vl + koff);
        *(unsigned*)&Khi[0][skey][se0] = kh1;
        *(unsigned*)&Klo[0][skey][se0] = kl1;
        Vthi[0][se0+0][skey] = (short)(vh1 & 0xffff);
        Vthi[0][se0+1][skey] = (short)(vh1 >> 16);
        Vtlo[0][se0+0][skey] = (short)(vl1 & 0xffff);
        Vtlo[0][se0+1][skey] = (short)(vl1 >> 16);
    }
    __syncthreads();

    f32x4 O[2][2];
    #pragma unroll
    for (int tq=0;tq<2;++tq)
        #pragma unroll
        for (int td=0;td<2;++td) O[tq][td] = (f32x4){0.f,0.f,0.f,0.f};
    float lpart[2] = {0.f, 0.f};

    ATTN_CHUNK(0, dc00,dc01,dc10,dc11, dn00,dn01,dn10,dn11)
    ATTN_CHUNK(1, dn00,dn01,dn10,dn11, dc00,dc01,dc10,dc11)
    ATTN_CHUNK(2, dc00,dc01,dc10,dc11, dn00,dn01,dn10,dn11)
    ATTN_CHUNK(3, dn00,dn01,dn10,dn11, dc00,dc01,dc10,dc11)
    ATTN_CHUNK(4, dc00,dc01,dc10,dc11, dn00,dn01,dn10,dn11)
    ATTN_CHUNK(5, dn00,dn01,dn10,dn11, dc00,dc01,dc10,dc11)
    ATTN_CHUNK(6, dc00,dc01,dc10,dc11, dn00,dn01,dn10,dn11)
    ATTN_CHUNK(7, dn00,dn01,dn10,dn11, dc00,dc01,dc10,dc11)

    float inv[2];
    #pragma unroll
    for (int tq = 0; tq < 2; ++tq) {
        float s = lpart[tq];
        s += __shfl_xor(s, 16);
        s += __shfl_xor(s, 32);
        inv[tq] = 1.f / s;
    }
    #pragma unroll
    for (int tq = 0; tq < 2; ++tq)
        #pragma unroll
        for (int td = 0; td < 2; ++td) {
            float v0 = O[tq][td][0] * inv[tq];
            float v1 = O[tq][td][1] * inv[tq];
            float v2 = O[tq][td][2] * inv[tq];
            float v3 = O[tq][td][3] * inv[tq];
            unsigned u0 = __float_as_uint(v0), u1 = __float_as_uint(v1);
            unsigned u2 = __float_as_uint(v2), u3 = __float_as_uint(v3);
            float r0 = v0 - __uint_as_float(u0 & 0xffff0000u);
            float r1 = v1 - __uint_as_float(u1 & 0xffff0000u);
            float r2 = v2 - __uint_as_float(u2 & 0xffff0000u);
            float r3 = v3 - __uint_as_float(u3 & 0xffff0000u);
            uint2 hiq, loq;
            hiq.x = (u0 >> 16) | (u1 & 0xffff0000u);
            hiq.y = (u2 >> 16) | (u3 & 0xffff0000u);
            loq.x = (__float_as_uint(r0) >> 16) | (__float_as_uint(r1) & 0xffff0000u);
            loq.y = (__float_as_uint(r2) >> 16) | (__float_as_uint(r3) & 0xffff0000u);
            int q = q0 + tq*16 + li;
            size_t base = ((size_t)b*Ng + q)*Dg + h*HDg + td*16 + g*4;
            *(uint2*)&AOh[base] = hiq;
            *(uint2*)&AOl[base] = loq;
        }
}

// ---------------- K3: output projection + fused pooling-score partials ------
__global__ __launch_bounds__(512, 4) void out_mm(
    const short* __restrict__ aoh, const short* __restrict__ aol,
    const short* __restrict__ bth, const short* __restrict__ btl,
    const float* __restrict__ bo, const float* __restrict__ pw,
    float* __restrict__ enc, float* __restrict__ score_part)
{
    __shared__ __align__(16) short lds[2][16384];
    const int tid = threadIdx.x;
    const int lane = tid & 63, w = tid >> 6;
    const int g = lane >> 4, li = lane & 15;
    const int wr = w >> 2, wc = w & 3;
    const int m0 = blockIdx.x * 128, n0 = blockIdx.y * 128;
    const int sr = tid >> 2, sc = (tid & 3) * 8;
    const int wbase = w * 512;
    f32x4 acc[4][2];
    #pragma unroll
    for (int i = 0; i < 4; ++i)
        #pragma unroll
        for (int j = 0; j < 2; ++j) acc[i][j] = (f32x4){0.f,0.f,0.f,0.f};

    {
        size_t ga = (size_t)(m0 + sr)*256 + sc;
        size_t gb = (size_t)(n0 + sr)*256 + sc;
        gload16(aoh + ga, &lds[0][        wbase]);
        gload16(aol + ga, &lds[0][ 4096 + wbase]);
        gload16(bth + gb, &lds[0][ 8192 + wbase]);
        gload16(btl + gb, &lds[0][12288 + wbase]);
    }
    __syncthreads();

    for (int k = 0; k < 8; ++k) {
        const int cur = k & 1;
        if (k < 7) {
            const int nb = cur ^ 1;
            int k0n = (k+1)*32;
            size_t ga = (size_t)(m0 + sr)*256 + k0n + sc;
            size_t gb = (size_t)(n0 + sr)*256 + k0n + sc;
            gload16(aoh + ga, &lds[nb][        wbase]);
            gload16(aol + ga, &lds[nb][ 4096 + wbase]);
            gload16(bth + gb, &lds[nb][ 8192 + wbase]);
            gload16(btl + gb, &lds[nb][12288 + wbase]);
        }
        bf16x8 ah[4], al[4], bh[2], bl[2];
        #pragma unroll
        for (int i = 0; i < 4; ++i) {
            int row = wr*64 + i*16 + li;
            ah[i] = *(const bf16x8*)&lds[cur][       row*32 + g*8];
            al[i] = *(const bf16x8*)&lds[cur][4096 + row*32 + g*8];
        }
        #pragma unroll
        for (int j = 0; j < 2; ++j) {
            int row = wc*32 + j*16 + li;
            bh[j] = *(const bf16x8*)&lds[cur][ 8192 + row*32 + g*8];
            bl[j] = *(const bf16x8*)&lds[cur][12288 + row*32 + g*8];
        }
        #pragma unroll
        for (int i = 0; i < 4; ++i)
            #pragma unroll
            for (int j = 0; j < 2; ++j) {
                acc[i][j] = __builtin_amdgcn_mfma_f32_16x16x32_bf16(bh[j], ah[i], acc[i][j], 0,0,0);
                acc[i][j] = __builtin_amdgcn_mfma_f32_16x16x32_bf16(bl[j], ah[i], acc[i][j], 0,0,0);
                acc[i][j] = __builtin_amdgcn_mfma_f32_16x16x32_bf16(bh[j], al[i], acc[i][j], 0,0,0);
            }
        __syncthreads();
    }
    const int pslot = blockIdx.y * 4 + wc;
    #pragma unroll
    for (int i = 0; i < 4; ++i) {
        int mrow = m0 + wr*64 + i*16 + li;
        float s = 0.f;
        #pragma unroll
        for (int j = 0; j < 2; ++j) {
            int c0 = n0 + wc*32 + j*16 + g*4;
            float4 bo4 = *(const float4*)(bo + c0);
            float4 pw4 = *(const float4*)(pw + c0);
            float4 v;
            v.x = acc[i][j][0] + bo4.x;
            v.y = acc[i][j][1] + bo4.y;
            v.z = acc[i][j][2] + bo4.z;
            v.w = acc[i][j][3] + bo4.w;
            *(float4*)&enc[(size_t)mrow*Dg + c0] = v;
            s += v.x*pw4.x + v.y*pw4.y + v.z*pw4.z + v.w*pw4.w;
        }
        s += __shfl_xor(s, 16);
        s += __shfl_xor(s, 32);
        if (g == 0) score_part[(size_t)pslot * BNg + mrow] = s;
    }
}

// ---------------- norm ----------------
__global__ void norm_kernel(const float* __restrict__ pw, float* __restrict__ inv_norm)
{
    int t = threadIdx.x;
    float s = 0.f;
    for (int d = t; d < Dg; d += 64) s = fmaf(pw[d], pw[d], s);
    #pragma unroll
    for (int off = 32; off > 0; off >>= 1) s += __shfl_xor(s, off);
    if (t == 0) *inv_norm = 1.0f / sqrtf(s);
}

// ---------------- K5: per-graph exact top-K via rank count ----------------
__global__ __launch_bounds__(256) void topk_kernel(
    const float* __restrict__ score_part, float* __restrict__ vals, int* __restrict__ idxs,
    int* __restrict__ new_id, float* __restrict__ out_batch)
{
    __shared__ float sh[Ng];
    int bgr = blockIdx.x, t = threadIdx.x;
    int row = bgr * Ng + t;
    float mine = 0.f;
    #pragma unroll
    for (int p = 0; p < 8; ++p) mine += score_part[(size_t)p * BNg + row];
    sh[t] = mine;
    __syncthreads();
    int cnt = 0;
    for (int j = 0; j < Ng; ++j) {
        float v = sh[j];
        cnt += (v > mine || (v == mine && j < t)) ? 1 : 0;
    }
    if (cnt < Kg) {
        int pos = bgr * Kg + cnt;
        vals[pos] = mine;
        idxs[pos] = t;
        new_id[bgr * Ng + t] = pos;
        out_batch[pos] = (float)bgr;
    } else {
        new_id[bgr * Ng + t] = SENT;
    }
}

// ---------------- K6: gather + tanh scale ----------------
__global__ __launch_bounds__(256) void subx_kernel(
    const float* __restrict__ enc, const float* __restrict__ vals,
    const int* __restrict__ idxs, const float* __restrict__ inv_norm,
    float* __restrict__ out_subx)
{
    int j    = blockIdx.x * 4 + (threadIdx.x >> 6);
    int lane = threadIdx.x & 63;
    int bgr  = j >> 7;
    int src  = bgr * Ng + idxs[j];
    float scale = tanhf(vals[j] * (*inv_norm));
    float4 v = reinterpret_cast<const float4*>(enc + (size_t)src * Dg)[lane];
    v.x *= scale; v.y *= scale; v.z *= scale; v.w *= scale;
    reinterpret_cast<float4*>(out_subx + (size_t)j * Dg)[lane] = v;
}

// ---------------- edge pipeline ----------------
__global__ __launch_bounds__(256) void edge_hist(
    const int* __restrict__ ei, const int* __restrict__ new_id, int* __restrict__ counts)
{
    int e = blockIdx.x * 256 + threadIdx.x;
    int r = new_id[ei[e]];
    int c = new_id[ei[Eg + e]];
    if (r != SENT && c != SENT) atomicAdd(&counts[r], 1);
}

__global__ __launch_bounds__(256) void scan_kernel(
    const int* __restrict__ counts, int* __restrict__ offsets)
{
    __shared__ int sums[256];
    int t = threadIdx.x;
    int base = t * 64;
    int s = 0;
    for (int i = 0; i < 64; ++i) s += counts[base + i];
    sums[t] = s;
    __syncthreads();
    for (int off = 1; off < 256; off <<= 1) {
        int add = (t >= off) ? sums[t - off] : 0;
        __syncthreads();
        sums[t] += add;
        __syncthreads();
    }
    int run = sums[t] - s;
    for (int i = 0; i < 64; ++i) { offsets[base + i] = run; run += counts[base + i]; }
    if (t == 255) offsets[SENT] = run;
}

__global__ __launch_bounds__(256) void edge_scatter(
    const int* __restrict__ ei, const int* __restrict__ new_id,
    const int* __restrict__ offsets, int* __restrict__ cursor, int* __restrict__ bucket)
{
    int e = blockIdx.x * 256 + threadIdx.x;
    int r = new_id[ei[e]];
    int c = new_id[ei[Eg + e]];
    if (r != SENT && c != SENT) {
        int pos = offsets[r] + atomicAdd(&cursor[r], 1);
        bucket[pos] = c;
    }
}

__global__ __launch_bounds__(256) void edge_sort_emit(
    const int* __restrict__ offsets, int* bucket, float* __restrict__ out_edges)
{
    int r = blockIdx.x * 256 + threadIdx.x;
    int s = offsets[r], e = offsets[r + 1];
    for (int i = s + 1; i < e; ++i) {
        int key = bucket[i];
        int j = i - 1;
        while (j >= s && bucket[j] > key) { bucket[j+1] = bucket[j]; --j; }
        bucket[j+1] = key;
    }
    float rf = (float)r;
    for (int i = s; i < e; ++i) {
        out_edges[i]      = rf;
        out_edges[Eg + i] = (float)bucket[i];
    }
}

__global__ __launch_bounds__(256) void edge_fill(
    const int* __restrict__ offsets, float* __restrict__ out_edges)
{
    int p = blockIdx.x * 256 + threadIdx.x;
    if (p >= offsets[SENT]) {
        out_edges[p]      = (float)SENT;
        out_edges[Eg + p] = (float)SENT;
    }
}

// ---------------- launch ----------------
extern "C" void kernel_launch(void* const* d_in, const int* in_sizes, int n_in,
                              void* d_out, int out_size, void* d_ws, size_t ws_size,
                              hipStream_t stream)
{
    const float* x    = (const float*)d_in[0];
    const float* dist = (const float*)d_in[2];
    const int*   ei   = (const int*)d_in[3];
    const float* Wq = (const float*)d_in[5];
    const float* bq = (const float*)d_in[6];
    const float* Wk = (const float*)d_in[7];
    const float* bk = (const float*)d_in[8];
    const float* Wv = (const float*)d_in[9];
    const float* bv = (const float*)d_in[10];
    const float* Wo = (const float*)d_in[11];
    const float* bo = (const float*)d_in[12];
    const float* pw = (const float*)d_in[13];

    float* out       = (float*)d_out;
    float* enc_out   = out;                     // [B*N*D]
    float* subx_out  = out + 8388608;           // [B*K*D]
    float* edge_out  = out + 12582912;          // [2*E]
    float* batch_out = out + 13631488;          // [B*K]

    float* ws      = (float*)d_ws;
    short* Qh      = (short*)ws;                 // 8,388,608 shorts each
    short* Ql      = (short*)(ws + 4194304);
    short* Kh      = (short*)(ws + 8388608);
    short* Kl      = (short*)(ws + 12582912);
    short* Vh      = (short*)(ws + 16777216);
    short* Vl      = (short*)(ws + 20971520);
    short* xh      = (short*)(ws + 25165824);    // 8,388,608 shorts
    short* xl      = (short*)(ws + 29360128);
    short* AOh     = xh;                         // alias after split_x consumed
    short* AOl     = xl;
    short* WTh     = (short*)(ws + 33554432);    // 4*65536 shorts
    short* WTl     = (short*)(ws + 33685504);
    float* vals    = ws + 33849344;              // 16384
    int*   idxs    = (int*)(ws + 33865728);      // 16384
    int*   new_id  = (int*)(ws + 33882112);      // 32768
    int*   counts  = (int*)(ws + 33914880);      // 16384
    int*   offsets = (int*)(ws + 33931264);      // 16416
    int*   cursor  = (int*)(ws + 33947680);      // 16384
    float* inv_nm  = ws + 33964064;              // 32
    int*   bucket  = (int*)(ws + 33964096);      // 524288
    float* score_part = ws + 34488384;           // 8*32768 = 262144

    hipMemsetAsync(counts, 0, SENT * sizeof(int), stream);
    hipMemsetAsync(cursor, 0, SENT * sizeof(int), stream);

    split_x       <<<dim3(4096),               256, 0, stream>>>(x, xh, xl);
    wprep         <<<dim3(64),                 256, 0, stream>>>(Wq, Wk, Wv, Wo, WTh, WTl);
    norm_kernel   <<<dim3(1),                   64, 0, stream>>>(pw, inv_nm);
    qkv_mm        <<<dim3(BNg/128, Dg/128, 3), 512, 0, stream>>>(xh, xl, WTh, WTl, bq, bk, bv,
                                                                 Qh, Ql, Kh, Kl, Vh, Vl);
    attn_mfma     <<<dim3(Bg*Hg),              512, 0, stream>>>(Qh, Ql, Kh, Kl, Vh, Vl, dist, AOh, AOl);
    out_mm        <<<dim3(BNg/128, Dg/128),    512, 0, stream>>>(AOh, AOl, WTh + 3*65536, WTl + 3*65536,
                                                                 bo, pw, enc_out, score_part);
    topk_kernel   <<<dim3(Bg),                 256, 0, stream>>>(score_part, vals, idxs, new_id, batch_out);
    subx_kernel   <<<dim3((Bg*Kg)/4),          256, 0, stream>>>(enc_out, vals, idxs, inv_nm, subx_out);
    edge_hist     <<<dim3(Eg/256),             256, 0, stream>>>(ei, new_id, counts);
    scan_kernel   <<<dim3(1),                  256, 0, stream>>>(counts, offsets);
    edge_scatter  <<<dim3(Eg/256),             256, 0, stream>>>(ei, new_id, offsets, cursor, bucket);
    edge_sort_emit<<<dim3(SENT/256),           256, 0, stream>>>(offsets, bucket, edge_out);
    edge_fill     <<<dim3(Eg/256),             256, 0, stream>>>(offsets, edge_out);
    (void)in_sizes; (void)n_in; (void)out_size; (void)ws_size;
}